// Round 26
// baseline (374.224 us; speedup 1.0000x reference)
//
#include <hip/hip_runtime.h>
#include <math.h>

// Problem constants (B=16, H=W=56, C=256)
#define BB   16
#define HH   56
#define WW   56
#define NN   (HH*WW)        // 3136
#define CC   256
#define CD   64
#define AD   192
#define NH   8
#define HG   4
#define HD   24
#define HID  1024
#define M1   49
#define M2   196
#define BNR  (BB*NN)        // 50176

typedef __attribute__((ext_vector_type(8))) short s8v;       // 8 bf16/f16 bit-patterns
typedef __attribute__((ext_vector_type(4))) short s4v;
typedef __attribute__((ext_vector_type(4))) float f4v;
typedef __attribute__((ext_vector_type(8))) _Float16 h8v;    // 8 f16
typedef __attribute__((ext_vector_type(2))) _Float16 h2v;    // 2 f16 (packed math)

// tanh-form GELU; max dev from erf-GELU ~3e-4
__device__ __forceinline__ float gelu_f(float x) {
    float u = x * (1.0f + 0.044715f * x * x);
    float t = __expf(-1.5957691216f * u);
    return x * __builtin_amdgcn_rcpf(1.0f + t);
}
__device__ __forceinline__ ushort f2bf(float f) {
    union { float f; uint32_t u; } c; c.f = f;
    uint32_t u = c.u;
    return (ushort)((u + 0x7fffu + ((u >> 16) & 1u)) >> 16);
}
__device__ __forceinline__ float bf2f(ushort u) {
    union { uint32_t u; float f; } c; c.u = ((uint32_t)u) << 16;
    return c.f;
}
__device__ __forceinline__ ushort f2h(float f) {
    union { _Float16 h; ushort u; } c; c.h = (_Float16)f;
    return c.u;
}
// async global->LDS, 16B per lane; dest = wave-uniform base + lane*16
__device__ __forceinline__ void load_lds16(const void* gsrc, void* ldst) {
    __builtin_amdgcn_global_load_lds(
        (const __attribute__((address_space(1))) void*)gsrc,
        (__attribute__((address_space(3))) void*)ldst, 16, 0, 0);
}
// bijective XCD-chunked block swizzle (m204)
__device__ __forceinline__ int xcd_swz(int bid, int nwg) {
    int q = nwg >> 3, r = nwg & 7;
    int x = bid & 7, i = bid >> 3;
    return (x < r ? x * (q + 1) : r * (q + 1) + (x - r) * q) + i;
}

// ---------------- fused weight prep: all converts/transposes in ONE launch ----------------
__global__ __launch_bounds__(256) void wprep_kernel(
        const float* __restrict__ qw, const float* __restrict__ k1,
        const float* __restrict__ k2, const float* __restrict__ pw,
        const float* __restrict__ f1, const float* __restrict__ f2,
        const float* __restrict__ cw, const float* __restrict__ lw,
        const float* __restrict__ dw,
        ushort* __restrict__ wq, ushort* __restrict__ wkv1,
        ushort* __restrict__ wkv2, ushort* __restrict__ wpr,
        ushort* __restrict__ wf1, ushort* __restrict__ wf2,
        ushort* __restrict__ wcp, float* __restrict__ lpwt,
        ushort* __restrict__ dwwth) {
    int i = blockIdx.x * 256 + threadIdx.x;
    if (i < 36864) { wq[i] = f2bf(qw[i]); return; } i -= 36864;
    if (i < 36864) { wkv1[i] = f2bf(k1[i]); return; } i -= 36864;
    if (i < 36864) { wkv2[i] = f2bf(k2[i]); return; } i -= 36864;
    if (i < 65536) { wpr[i] = f2bf(pw[i]); return; } i -= 65536;
    if (i < 262144) { wf1[i] = f2bf(f1[i]); return; } i -= 262144;
    if (i < 262144) { wf2[i] = f2h(f2[i]); return; } i -= 262144;
    if (i < 36864) {
        int co = i / 576, k = i - co * 576;
        int tap = k >> 6, ci = k & 63;
        wcp[i] = f2bf(cw[co * 576 + ci * 9 + tap]);
        return;
    } i -= 36864;
    if (i < 2304) { int c = i / 9, t = i - c * 9; lpwt[t * CC + c] = lw[i]; return; } i -= 2304;
    if (i < 9216) { int c = i / 9, t = i - c * 9; dwwth[t * HID + c] = f2h(dw[i]); }
}

// ---------------- LPU x-walk: dw3x3 + bias + residual + fused LN1; 4 px/wave ----------------
__global__ __launch_bounds__(256) void lpu_kernel(const float* __restrict__ x,
        const float* __restrict__ wt, const float* __restrict__ bias,
        const float* __restrict__ n1g, const float* __restrict__ n1b,
        ushort* __restrict__ xbuf, ushort* __restrict__ ybuf) {
    int tid = threadIdx.x;
    int lane = tid & 63, wv = tid >> 6;
    int c = lane * 4;
    int grp = xcd_swz(blockIdx.x, NN / 16) * 4 + wv;
    int n0 = grp * 4;
    int h = n0 / WW, x0 = n0 - h * WW;
    int b = blockIdx.y;
    const float* xb = x + (size_t)b * NN * CC + c;
    float4 wreg[9];
#pragma unroll
    for (int t = 0; t < 9; ++t) wreg[t] = *(const float4*)(wt + t * CC + c);
    float4 bz = *(const float4*)(bias + c);
    float4 acc[4] = {bz, bz, bz, bz};
#pragma unroll
    for (int cx = 0; cx < 6; ++cx) {
        int wx = x0 + cx - 1;
        if ((unsigned)wx >= (unsigned)WW) continue;
#pragma unroll
        for (int ky = 0; ky < 3; ++ky) {
            int hy = h + ky - 1;
            if ((unsigned)hy >= (unsigned)HH) continue;
            float4 xv = *(const float4*)(xb + (size_t)(hy * WW + wx) * CC);
#pragma unroll
            for (int xo = 0; xo < 4; ++xo) {
                int kx = cx - xo;
                if (kx < 0 || kx > 2) continue;
                float4 wv4 = wreg[ky * 3 + kx];
                acc[xo].x = fmaf(xv.x, wv4.x, acc[xo].x);
                acc[xo].y = fmaf(xv.y, wv4.y, acc[xo].y);
                acc[xo].z = fmaf(xv.z, wv4.z, acc[xo].z);
                acc[xo].w = fmaf(xv.w, wv4.w, acc[xo].w);
            }
        }
    }
    float4 gv = *(const float4*)(n1g + c);
    float4 bv = *(const float4*)(n1b + c);
#pragma unroll
    for (int xo = 0; xo < 4; ++xo) {
        size_t o = ((size_t)b * NN + n0 + xo) * CC + c;
        float4 rv = *(const float4*)(x + o);
        float4 a = acc[xo];
        a.x += rv.x; a.y += rv.y; a.z += rv.z; a.w += rv.w;
        s4v xv4;
        xv4.x = (short)f2bf(a.x);
        xv4.y = (short)f2bf(a.y);
        xv4.z = (short)f2bf(a.z);
        xv4.w = (short)f2bf(a.w);
        *(s4v*)(xbuf + o) = xv4;
        float s = a.x + a.y + a.z + a.w;
        float sq = a.x * a.x + a.y * a.y + a.z * a.z + a.w * a.w;
#pragma unroll
        for (int off = 32; off >= 1; off >>= 1) {
            s += __shfl_xor(s, off, 64);
            sq += __shfl_xor(sq, off, 64);
        }
        float mean = s * (1.0f / 256.0f);
        float var = sq * (1.0f / 256.0f) - mean * mean;
        float rstd = rsqrtf(var + 1e-5f);
        s4v ov;
        ov.x = (short)f2bf((a.x - mean) * rstd * gv.x + bv.x);
        ov.y = (short)f2bf((a.y - mean) * rstd * gv.y + bv.y);
        ov.z = (short)f2bf((a.z - mean) * rstd * gv.z + bv.z);
        ov.w = (short)f2bf((a.w - mean) * rstd * gv.w + bv.w);
        *(s4v*)(ybuf + o) = ov;
    }
}

// ---------------- cp branch: implicit-GEMM conv + fused LN(64)+GELU epilogue ----------------
__global__ __launch_bounds__(256) void cpgemm_kernel(
        const ushort* __restrict__ y, const ushort* __restrict__ wt,
        const float* __restrict__ cb, const float* __restrict__ cng,
        const float* __restrict__ cnb, ushort* __restrict__ cat) {
    __shared__ __align__(16) ushort As[128 * 32];
    __shared__ __align__(16) ushort Ws[64 * 32];
    int tid = threadIdx.x;
    int wid = tid >> 6, lane = tid & 63;
    int rt = xcd_swz(blockIdx.x, BNR / 128) * 128;
    int r0 = tid >> 2, c0 = tid & 3;
    int r1 = r0 + 64;
    int tok0 = rt + r0, tok1 = rt + r1;
    int b0 = tok0 / NN, n0 = tok0 - b0 * NN, h0 = n0 / WW, w0 = n0 - h0 * WW;
    int b1 = tok1 / NN, n1 = tok1 - b1 * NN, h1 = n1 / WW, w1 = n1 - h1 * WW;
    const ushort* Wp = wt + (size_t)r0 * 576 + c0 * 8;
    int aw0 = (c0 ^ (r0 & 3)) << 3;
    f4v acc[2][4];
#pragma unroll
    for (int m = 0; m < 2; ++m)
#pragma unroll
        for (int n = 0; n < 4; ++n) acc[m][n] = (f4v)0.f;
    int lr = lane & 15, g4 = lane >> 4;
    int swz = (g4 ^ (lr & 3)) << 3;
    for (int kt = 0; kt < 576; kt += 32) {
        int tap = kt >> 6, ci0 = kt & 63;
        int t3 = tap / 3, dy = t3 - 1, dx = (tap - t3 * 3) - 1;
        s8v a0 = (s8v)0, a1 = (s8v)0;
        int hy0 = h0 + dy, wx0 = w0 + dx;
        if ((unsigned)hy0 < (unsigned)HH && (unsigned)wx0 < (unsigned)WW)
            a0 = *(const s8v*)(y + ((size_t)b0 * NN + hy0 * WW + wx0) * CC + ci0 + c0 * 8);
        int hy1 = h1 + dy, wx1 = w1 + dx;
        if ((unsigned)hy1 < (unsigned)HH && (unsigned)wx1 < (unsigned)WW)
            a1 = *(const s8v*)(y + ((size_t)b1 * NN + hy1 * WW + wx1) * CC + ci0 + c0 * 8);
        s8v wv = *(const s8v*)(Wp + kt);
        __syncthreads();
        *(s8v*)&As[r0 * 32 + aw0] = a0;
        *(s8v*)&As[r1 * 32 + aw0] = a1;
        *(s8v*)&Ws[r0 * 32 + aw0] = wv;
        __syncthreads();
        s8v af[2], bf[4];
#pragma unroll
        for (int m = 0; m < 2; ++m)
            af[m] = *(const s8v*)&As[(wid * 32 + m * 16 + lr) * 32 + swz];
#pragma unroll
        for (int n = 0; n < 4; ++n)
            bf[n] = *(const s8v*)&Ws[(n * 16 + lr) * 32 + swz];
#pragma unroll
        for (int m = 0; m < 2; ++m)
#pragma unroll
            for (int n = 0; n < 4; ++n)
                acc[m][n] = __builtin_amdgcn_mfma_f32_16x16x32_bf16(af[m], bf[n], acc[m][n], 0, 0, 0);
    }
    float gv[4], bv[4], cbv[4];
#pragma unroll
    for (int n = 0; n < 4; ++n) {
        int gc = n * 16 + lr;
        cbv[n] = cb[gc];
        gv[n] = cng[gc];
        bv[n] = cnb[gc];
    }
#pragma unroll
    for (int m = 0; m < 2; ++m)
#pragma unroll
        for (int r = 0; r < 4; ++r) {
            float s = 0.f, sq = 0.f;
#pragma unroll
            for (int n = 0; n < 4; ++n) {
                float v = acc[m][n][r] + cbv[n];
                acc[m][n][r] = v;
                s += v; sq += v * v;
            }
#pragma unroll
            for (int off = 1; off < 16; off <<= 1) {
                s += __shfl_xor(s, off, 64);
                sq += __shfl_xor(sq, off, 64);
            }
            float mean = s * (1.0f / 64.0f);
            float var = sq * (1.0f / 64.0f) - mean * mean;
            float rstd = rsqrtf(var + 1e-5f);
            int row = rt + wid * 32 + m * 16 + g4 * 4 + r;
            ushort* op = cat + (size_t)row * CC + 192;
#pragma unroll
            for (int n = 0; n < 4; ++n) {
                float v = (acc[m][n][r] - mean) * rstd * gv[n] + bv[n];
                op[n * 16 + lr] = f2bf(gelu_f(v));
            }
        }
}

// ---------------- SR conv (depthwise KSxKS stride KS) + LN(192) + GELU, bf16 io ----------------
template <int KS, int OW>
__global__ __launch_bounds__(192) void sr_kernel(const ushort* __restrict__ yap,
        const float* __restrict__ w, const float* __restrict__ bias,
        const float* __restrict__ g, const float* __restrict__ bt,
        ushort* __restrict__ out) {
    int ch = threadIdx.x;
    int m = blockIdx.x, b = blockIdx.y;
    int oh = m / OW, ow = m - oh * OW;
    const ushort* yb = yap + (size_t)b * NN * CC;
    float acc = bias[ch];
#pragma unroll
    for (int ky = 0; ky < KS; ++ky)
#pragma unroll
        for (int kx = 0; kx < KS; ++kx)
            acc = fmaf(bf2f(yb[(size_t)((oh * KS + ky) * WW + ow * KS + kx) * CC + ch]),
                       w[ch * KS * KS + ky * KS + kx], acc);
    __shared__ float red[2][3];
    float s = acc, sq = acc * acc;
#pragma unroll
    for (int off = 32; off >= 1; off >>= 1) {
        s += __shfl_xor(s, off, 64);
        sq += __shfl_xor(sq, off, 64);
    }
    int wv = threadIdx.x >> 6, lane = threadIdx.x & 63;
    if (lane == 0) { red[0][wv] = s; red[1][wv] = sq; }
    __syncthreads();
    s = red[0][0] + red[0][1] + red[0][2];
    sq = red[1][0] + red[1][1] + red[1][2];
    float mean = s * (1.0f / 192.0f);
    float var = sq * (1.0f / 192.0f) - mean * mean;
    float rstd = rsqrtf(var + 1e-5f);
    float v = (acc - mean) * rstd * g[ch] + bt[ch];
    out[((size_t)b * (OW * OW) + m) * AD + ch] = f2bf(gelu_f(v));
}

// ---------------- MFMA GEMM: 256x128 tile, 512 thr / 8 waves, 2-phase (q/kv) ----------------
// MODE bits: 1=bias(fp32), 2=residual(bf16, stride ldr), 4=output bf16, 8=output f16 (else fp32)
template <int MODE, int F16 = 0>
__global__ __launch_bounds__(512) void gemm_mfma(
        const ushort* __restrict__ A, int lda,
        const ushort* __restrict__ W, int K, int O,
        const float* __restrict__ bias,
        const ushort* __restrict__ res, int ldr,
        void* __restrict__ Cout, int ldc, int R) {
    __shared__ __align__(16) ushort As[2 * 256 * 32];   // 32KB
    __shared__ __align__(16) ushort Ws[2 * 128 * 32];   // 16KB
    int tid = threadIdx.x;
    int w8 = tid >> 6, lane = tid & 63;
    int wr = w8 >> 1, wc = w8 & 1;
    int nwg = gridDim.x * gridDim.y;
    int swzb = xcd_swz(blockIdx.y * gridDim.x + blockIdx.x, nwg);
    int rt = (swzb / gridDim.x) * 256, ot = (swzb % gridDim.x) * 128;
    int r0 = tid >> 2, cslot = tid & 3;
    int csrc = (cslot ^ (r0 & 3)) * 8;
    const ushort* Ap0 = A + (size_t)min(rt + r0, R - 1) * lda + csrc;
    const ushort* Ap1 = A + (size_t)min(rt + r0 + 128, R - 1) * lda + csrc;
    const ushort* Wp0 = W + (size_t)min(ot + r0, O - 1) * K + csrc;
    char* lA0 = (char*)As + w8 * 1024;
    char* lA1 = (char*)As + 8192 + w8 * 1024;
    char* lW0 = (char*)Ws + w8 * 1024;
    f4v acc[4][4];
#pragma unroll
    for (int m = 0; m < 4; ++m)
#pragma unroll
        for (int n = 0; n < 4; ++n) acc[m][n] = (f4v)0.f;
    int lr = lane & 15;
    int swz = ((lane >> 4) ^ (lr & 3)) << 3;
    load_lds16(Ap0, lA0);
    load_lds16(Ap1, lA1);
    load_lds16(Wp0, lW0);
    __syncthreads();
    int cur = 0;
    for (int kt = 0; kt < K; kt += 32) {
        if (kt + 32 < K) {
            int pa = (cur ^ 1) * 16384, pw = (cur ^ 1) * 8192;
            load_lds16(Ap0 + kt + 32, lA0 + pa);
            load_lds16(Ap1 + kt + 32, lA1 + pa);
            load_lds16(Wp0 + kt + 32, lW0 + pw);
        }
        const ushort* Ab = As + cur * 8192;
        const ushort* Wb = Ws + cur * 4096;
        s8v af[4], bf[4];
#pragma unroll
        for (int m = 0; m < 4; ++m)
            af[m] = *(const s8v*)&Ab[(wr * 64 + m * 16 + lr) * 32 + swz];
#pragma unroll
        for (int n = 0; n < 4; ++n)
            bf[n] = *(const s8v*)&Wb[(wc * 64 + n * 16 + lr) * 32 + swz];
#pragma unroll
        for (int m = 0; m < 4; ++m)
#pragma unroll
            for (int n = 0; n < 4; ++n) {
                if (F16) {
                    h8v ah = *(const h8v*)&af[m];
                    h8v bh = *(const h8v*)&bf[n];
                    acc[m][n] = __builtin_amdgcn_mfma_f32_16x16x32_f16(ah, bh, acc[m][n], 0, 0, 0);
                } else {
                    acc[m][n] = __builtin_amdgcn_mfma_f32_16x16x32_bf16(af[m], bf[n], acc[m][n], 0, 0, 0);
                }
            }
        __syncthreads();
        cur ^= 1;
    }
#pragma unroll
    for (int m = 0; m < 4; ++m)
#pragma unroll
        for (int n = 0; n < 4; ++n) {
            int gr = rt + wr * 64 + m * 16 + (lane >> 4) * 4;
            int gc = ot + wc * 64 + n * 16 + (lane & 15);
            if (gc >= O) continue;
#pragma unroll
            for (int r = 0; r < 4; ++r) {
                int row = gr + r;
                if (row >= R) continue;
                float v = acc[m][n][r];
                if (MODE & 1) v += bias[gc];
                if (MODE & 2) v += bf2f(res[(size_t)row * ldr + gc]);
                if (MODE & 4)      ((ushort*)Cout)[(size_t)row * ldc + gc] = f2bf(v);
                else if (MODE & 8) ((ushort*)Cout)[(size_t)row * ldc + gc] = f2h(v);
                else               ((float*)Cout)[(size_t)row * ldc + gc] = v;
            }
        }
}

// ---------------- 16-wave 8-phase GEMM: 256x256 tile, BK=32/phase, 2-slot 64KB LDS ----------------
// 1024 thr / 16 waves (4x4), each wave 64x64 out (acc 4x4, ~56 VGPR). 64KB -> 2 blocks/CU
// (8 waves/SIMD). Per phase: vmcnt(2) -> barrier -> ds_read+MFMA -> barrier -> STAGE(s+2).
// Requires R%256==0, O%256==0, K%32==0, K>=64. MODE as gemm_mfma.
template <int MODE, int F16 = 0>
__global__ __launch_bounds__(1024) void gemm_8ph(
        const ushort* __restrict__ A, int lda,
        const ushort* __restrict__ W, int K, int O,
        const float* __restrict__ bias,
        const ushort* __restrict__ res, int ldr,
        void* __restrict__ Cout, int ldc, int R) {
    __shared__ __align__(16) ushort Al[2 * 256 * 32];   // 32KB
    __shared__ __align__(16) ushort Wl[2 * 256 * 32];   // 32KB
    int tid = threadIdx.x;
    int w16 = tid >> 6, lane = tid & 63;
    int wr = w16 >> 2, wc = w16 & 3;          // 4 x 4 wave grid
    int nwg = gridDim.x * gridDim.y;
    int swzb = xcd_swz(blockIdx.y * gridDim.x + blockIdx.x, nwg);
    int rt = (swzb / gridDim.x) * 256, ot = (swzb % gridDim.x) * 256;
    int lr = lane & 15, g4 = lane >> 4;
    int swz = (g4 ^ (lr & 3)) << 3;
    int ar0 = tid >> 2, sp0 = tid & 3;        // 1024 units cover 256 rows x 4 slots
    int cs0 = ((sp0 ^ (ar0 & 3)) << 3);       // inverse-swizzled source K-slot
    const ushort* Ap0 = A + (size_t)(rt + ar0) * lda + cs0;
    const ushort* Wp0 = W + (size_t)(ot + ar0) * K + cs0;
    int d0 = w16 * 1024;                       // LDS dest byte offset (lane*16 implicit)
    f4v acc[4][4];
#pragma unroll
    for (int m = 0; m < 4; ++m)
#pragma unroll
        for (int n = 0; n < 4; ++n)
            acc[m][n] = (f4v)((MODE & 1) ? bias[ot + wc * 64 + n * 16 + lr] : 0.0f);
    auto STAGE = [&](int s) {
        int boff = (s & 1) * 16384;            // slot byte offset (16KB per slot per array)
        int kc = s * 32;
        load_lds16(Ap0 + kc, (char*)Al + boff + d0);
        load_lds16(Wp0 + kc, (char*)Wl + boff + d0);
    };
    int nS = K >> 5;                           // 32-K phases
    STAGE(0); STAGE(1);
    for (int s = 0; s < nS; ++s) {
        if (s == nS - 1) asm volatile("s_waitcnt vmcnt(0)" ::: "memory");
        else             asm volatile("s_waitcnt vmcnt(2)" ::: "memory");
        __builtin_amdgcn_s_barrier();
        __builtin_amdgcn_sched_barrier(0);
        int uoff = (s & 1) * 8192;             // ushort index offset
        const ushort* Ab = Al + uoff;
        const ushort* Wb = Wl + uoff;
        s8v af[4], bf[4];
#pragma unroll
        for (int m = 0; m < 4; ++m)
            af[m] = *(const s8v*)&Ab[(wr * 64 + m * 16 + lr) * 32 + swz];
#pragma unroll
        for (int n = 0; n < 4; ++n)
            bf[n] = *(const s8v*)&Wb[(wc * 64 + n * 16 + lr) * 32 + swz];
        __builtin_amdgcn_s_setprio(1);
#pragma unroll
        for (int m = 0; m < 4; ++m)
#pragma unroll
            for (int n = 0; n < 4; ++n) {
                if (F16) {
                    h8v ah = *(const h8v*)&af[m];
                    h8v bh = *(const h8v*)&bf[n];
                    acc[m][n] = __builtin_amdgcn_mfma_f32_16x16x32_f16(ah, bh, acc[m][n], 0, 0, 0);
                } else {
                    acc[m][n] = __builtin_amdgcn_mfma_f32_16x16x32_bf16(af[m], bf[n], acc[m][n], 0, 0, 0);
                }
            }
        __builtin_amdgcn_s_setprio(0);
        __builtin_amdgcn_s_barrier();          // all waves done reading slot s&1
        if (s + 2 < nS) STAGE(s + 2);          // overwrite slot s&1 (now free)
    }
#pragma unroll
    for (int m = 0; m < 4; ++m) {
        int gr = rt + wr * 64 + m * 16 + g4 * 4;
#pragma unroll
        for (int n = 0; n < 4; ++n) {
            int gc = ot + wc * 64 + n * 16 + lr;
#pragma unroll
            for (int r = 0; r < 4; ++r) {
                int row = gr + r;
                float v = acc[m][n][r];
                if (MODE & 2) v += bf2f(res[(size_t)row * ldr + gc]);
                if (MODE & 4)      ((ushort*)Cout)[(size_t)row * ldc + gc] = f2bf(v);
                else if (MODE & 8) ((ushort*)Cout)[(size_t)row * ldc + gc] = f2h(v);
                else               ((float*)Cout)[(size_t)row * ldc + gc] = v;
            }
        }
    }
}

// ---------------- proj (O=256) + bias + residual + fused LN2 ----------------
__global__ __launch_bounds__(512) void projln_kernel(
        const ushort* __restrict__ A, const ushort* __restrict__ W,
        const float* __restrict__ bias,
        const float* __restrict__ n2g, const float* __restrict__ n2b,
        ushort* __restrict__ xbuf, ushort* __restrict__ ybuf) {
    __shared__ __align__(16) ushort As[128 * 32];   // 8KB
    __shared__ __align__(16) ushort Ws[256 * 32];   // 16KB
    int tid = threadIdx.x;
    int w8 = tid >> 6, lane = tid & 63;
    int rt = xcd_swz(blockIdx.x, BNR / 128) * 128;
    int r0 = tid >> 2, cslot = tid & 3;
    int csrc = (cslot ^ (r0 & 3)) * 8;
    const ushort* Ap0 = A + (size_t)(rt + r0) * CC + csrc;
    const ushort* Wp0 = W + (size_t)r0 * CC + csrc;
    const ushort* Wp1 = W + (size_t)(r0 + 128) * CC + csrc;
    char* lA0 = (char*)As + w8 * 1024;
    char* lW0 = (char*)Ws + w8 * 1024;
    char* lW1 = (char*)Ws + 8192 + w8 * 1024;
    int lr = lane & 15, g4 = lane >> 4;
    int swz = (g4 ^ (lr & 3)) << 3;
    f4v acc[16];
#pragma unroll
    for (int n = 0; n < 16; ++n) acc[n] = (f4v)(bias[n * 16 + lr]);
    for (int kt = 0; kt < CC; kt += 32) {
        __syncthreads();
        load_lds16(Ap0 + kt, lA0);
        load_lds16(Wp0 + kt, lW0);
        load_lds16(Wp1 + kt, lW1);
        __syncthreads();
        s8v af = *(const s8v*)&As[(w8 * 16 + lr) * 32 + swz];
#pragma unroll
        for (int n = 0; n < 16; ++n) {
            s8v bf = *(const s8v*)&Ws[(n * 16 + lr) * 32 + swz];
            acc[n] = __builtin_amdgcn_mfma_f32_16x16x32_bf16(af, bf, acc[n], 0, 0, 0);
        }
    }
#pragma unroll
    for (int r = 0; r < 4; ++r) {
        int row = rt + w8 * 16 + g4 * 4 + r;
        ushort* xr = xbuf + (size_t)row * CC;
        ushort* yr = ybuf + (size_t)row * CC;
        float s = 0.f, sq = 0.f;
#pragma unroll
        for (int n = 0; n < 16; ++n) {
            float v = acc[n][r] + bf2f(xr[n * 16 + lr]);
            acc[n][r] = v;
            s += v; sq += v * v;
        }
#pragma unroll
        for (int off = 1; off < 16; off <<= 1) {
            s += __shfl_xor(s, off, 64);
            sq += __shfl_xor(sq, off, 64);
        }
        float mean = s * (1.0f / 256.0f);
        float var = sq * (1.0f / 256.0f) - mean * mean;
        float rstd = rsqrtf(var + 1e-5f);
#pragma unroll
        for (int n = 0; n < 16; ++n) {
            int col = n * 16 + lr;
            float v = acc[n][r];
            xr[col] = f2bf(v);
            yr[col] = f2bf((v - mean) * rstd * n2g[col] + n2b[col]);
        }
    }
}

// ---------------- MFMA attention, 256 queries/block, vectorized swizzled staging ----------------
template <int M, int MP, int HOFF>
__global__ __launch_bounds__(256) void attn_mfma(const ushort* __restrict__ q,
        const ushort* __restrict__ kvb, ushort* __restrict__ cat) {
    constexpr int NT = MP / 16;
    constexpr int NCH = MP / 32;
    __shared__ __align__(16) ushort Kl[MP * 32];
    __shared__ __align__(16) ushort VT[32 * MP];
    int g = blockIdx.y, b = blockIdx.z;
    int h = HOFF + g;
    int tid = threadIdx.x;
    for (int i = tid; i < MP * 4; i += 256) ((s8v*)Kl)[i] = (s8v)0;
    for (int i = tid; i < MP * 4; i += 256) ((s8v*)VT)[i] = (s8v)0;
    __syncthreads();
    for (int u = tid; u < M * 3; u += 256) {
        int m = u / 3, d0 = u - m * 3;
        s8v kv8 = *(const s8v*)(kvb + ((size_t)b * M + m) * AD + g * HD + d0 * 8);
        *(s8v*)&Kl[m * 32 + ((d0 ^ (m & 3)) << 3)] = kv8;
    }
    for (int u = tid; u < M * 3; u += 256) {
        int m = u / 3, d0 = u - m * 3;
        s8v vv = *(const s8v*)(kvb + ((size_t)b * M + m) * AD + 96 + g * HD + d0 * 8);
        int c = m >> 5, mm = m & 31;
        int gg = (mm >> 2) & 3;
        int t = (mm & 3) + ((mm & 16) >> 2);
#pragma unroll
        for (int j = 0; j < 8; ++j) {
            int d = d0 * 8 + j;
            VT[d * MP + ((c * 4 + (gg ^ (d & 3))) << 3) + t] = (ushort)vv[j];
        }
    }
    __syncthreads();
    int w = tid >> 6, lane = tid & 63;
    int ln = lane & 15, g4 = lane >> 4;
    int swz = (g4 ^ (ln & 3)) << 3;
    const float scale = 0.20412414523193154f;  // 24^-0.5
    for (int nt = 0; nt < 4; ++nt) {
        int nbase = blockIdx.x * 256 + nt * 64;
        if (nbase >= NN) break;
        int n0 = nbase + w * 16 + ln;
        s8v qf = (s8v)0;
        if (g4 < 3) qf = *(const s8v*)(q + ((size_t)b * NN + n0) * AD + h * HD + g4 * 8);
        f4v sa[NT];
#pragma unroll
        for (int t = 0; t < NT; ++t) sa[t] = (f4v)0.f;
#pragma unroll
        for (int t = 0; t < NT; ++t) {
            s8v kf = *(const s8v*)&Kl[(t * 16 + ln) * 32 + swz];
            sa[t] = __builtin_amdgcn_mfma_f32_16x16x32_bf16(kf, qf, sa[t], 0, 0, 0);
        }
        float mx = -3.0e38f;
#pragma unroll
        for (int t = 0; t < NT; ++t)
#pragma unroll
            for (int r = 0; r < 4; ++r) {
                int m = t * 16 + g4 * 4 + r;
                float v = (m < M) ? sa[t][r] * scale : -3.0e38f;
                sa[t][r] = v;
                mx = fmaxf(mx, v);
            }
        mx = fmaxf(mx, __shfl_xor(mx, 16, 64));
        mx = fmaxf(mx, __shfl_xor(mx, 32, 64));
        float sum = 0.f;
#pragma unroll
        for (int t = 0; t < NT; ++t)
#pragma unroll
            for (int r = 0; r < 4; ++r) {
                float p = __expf(sa[t][r] - mx);
                sa[t][r] = p;
                sum += p;
            }
        sum += __shfl_xor(sum, 16, 64);
        sum += __shfl_xor(sum, 32, 64);
        float inv = 1.0f / sum;
        f4v oa[2] = {(f4v)0.f, (f4v)0.f};
#pragma unroll
        for (int c = 0; c < NCH; ++c) {
            s8v pb;
#pragma unroll
            for (int t = 0; t < 4; ++t) {
                pb[t]     = (short)f2bf(sa[c * 2][t]);
                pb[4 + t] = (short)f2bf(sa[c * 2 + 1][t]);
            }
#pragma unroll
            for (int dt = 0; dt < 2; ++dt) {
                s8v vf = *(const s8v*)&VT[(dt * 16 + ln) * MP + c * 32 + swz];
                oa[dt] = __builtin_amdgcn_mfma_f32_16x16x32_bf16(vf, pb, oa[dt], 0, 0, 0);
            }
        }
        ushort* op = cat + ((size_t)b * NN + n0) * CC + h * HD;
        s4v o0;
#pragma unroll
        for (int r = 0; r < 4; ++r) o0[r] = (short)f2bf(oa[0][r] * inv);
        *(s4v*)(op + g4 * 4) = o0;
        if (g4 < 2) {
            s4v o1;
#pragma unroll
            for (int r = 0; r < 4; ++r) o1[r] = (short)f2bf(oa[1][r] * inv);
            *(s4v*)(op + 16 + g4 * 4) = o1;
        }
    }
}

// ---------------- depthwise 3x3 hid=1024: x-walk, f16 packed math ----------------
__global__ __launch_bounds__(256) void dwconv_kernel(const ushort* __restrict__ z1,
        const ushort* __restrict__ wt, const float* __restrict__ bias,
        ushort* __restrict__ z2) {
    int bid = xcd_swz(blockIdx.x, HH * 7);
    int h = bid / 7, bx = bid - h * 7;
    int b = blockIdx.y;
    int c = (threadIdx.x & 127) * 8;
    int x0 = bx * 8 + (threadIdx.x >> 7) * 4;
    const ushort* zrow = z1 + ((size_t)b * NN + h * WW) * HID + c;
    h2v wreg[9][4];
#pragma unroll
    for (int t = 0; t < 9; ++t) {
        s8v w8 = *(const s8v*)(wt + t * HID + c);
        const h2v* wp = (const h2v*)&w8;
#pragma unroll
        for (int p = 0; p < 4; ++p) wreg[t][p] = wp[p];
    }
    h2v acc[4][4];
    {
        float4 b0 = *(const float4*)(bias + c);
        float4 b1 = *(const float4*)(bias + c + 4);
        h2v bz[4];
        bz[0][0] = (_Float16)b0.x; bz[0][1] = (_Float16)b0.y;
        bz[1][0] = (_Float16)b0.z; bz[1][1] = (_Float16)b0.w;
        bz[2][0] = (_Float16)b1.x; bz[2][1] = (_Float16)b1.y;
        bz[3][0] = (_Float16)b1.z; bz[3][1] = (_Float16)b1.w;
#pragma unroll
        for (int xo = 0; xo < 4; ++xo)
#pragma unroll
            for (int p = 0; p < 4; ++p) acc[xo][p] = bz[p];
    }
#pragma unroll
    for (int cx = 0; cx < 6; ++cx) {
        int wx = x0 + cx - 1;
        if ((unsigned)wx >= (unsigned)WW) continue;
#pragma unroll
        for (int ky = 0; ky < 3; ++ky) {
            int hy = h + ky - 1;
            if ((unsigned)hy >= (unsigned)HH) continue;
            s8v v = *(const s8v*)(zrow + ((size_t)(ky - 1) * WW + wx) * HID);
            const h2v* v2 = (const h2v*)&v;
#pragma unroll
            for (int xo = 0; xo < 4; ++xo) {
                int kx = cx - xo;
                if (kx < 0 || kx > 2) continue;
#pragma unroll
                for (int p = 0; p < 4; ++p)
                    acc[xo][p] = v2[p] * wreg[ky * 3 + kx][p] + acc[xo][p];
            }
        }
    }
    ushort* zo = z2 + ((size_t)b * NN + h * WW + x0) * HID + c;
#pragma unroll
    for (int xo = 0; xo < 4; ++xo) {
        s8v o;
#pragma unroll
        for (int p = 0; p < 4; ++p) {
            o[p * 2]     = (short)f2h(gelu_f((float)acc[xo][p][0]));
            o[p * 2 + 1] = (short)f2h(gelu_f((float)acc[xo][p][1]));
        }
        *(s8v*)(zo + (size_t)xo * HID) = o;
    }
}

extern "C" void kernel_launch(void* const* d_in, const int* in_sizes, int n_in,
                              void* d_out, int out_size, void* d_ws, size_t ws_size,
                              hipStream_t stream) {
    const float* x      = (const float*)d_in[0];
    const float* lpu_w  = (const float*)d_in[3];
    const float* lpu_b  = (const float*)d_in[4];
    const float* n1_g   = (const float*)d_in[5];
    const float* n1_b   = (const float*)d_in[6];
    const float* c2_w   = (const float*)d_in[7];
    const float* c2_b   = (const float*)d_in[8];
    const float* cn_g   = (const float*)d_in[9];
    const float* cn_b   = (const float*)d_in[10];
    const float* q_w    = (const float*)d_in[11];
    const float* sr1_w  = (const float*)d_in[12];
    const float* sr1_b  = (const float*)d_in[13];
    const float* an1_g  = (const float*)d_in[14];
    const float* an1_b  = (const float*)d_in[15];
    const float* sr2_w  = (const float*)d_in[16];
    const float* sr2_b  = (const float*)d_in[17];
    const float* an2_g  = (const float*)d_in[18];
    const float* an2_b  = (const float*)d_in[19];
    const float* kv1_w  = (const float*)d_in[20];
    const float* kv2_w  = (const float*)d_in[21];
    const float* proj_w = (const float*)d_in[22];
    const float* proj_b = (const float*)d_in[23];
    const float* n2_g   = (const float*)d_in[24];
    const float* n2_b   = (const float*)d_in[25];
    const float* fc1_w  = (const float*)d_in[26];
    const float* fc1_b  = (const float*)d_in[27];
    const float* dw_w   = (const float*)d_in[28];
    const float* dw_b   = (const float*)d_in[29];
    const float* fc2_w  = (const float*)d_in[30];
    const float* fc2_b  = (const float*)d_in[31];
    float* out = (float*)d_out;

    char* ws = (char*)d_ws;
    size_t off = 0;
    auto allocB = [&](size_t bytes) {
        char* p = ws + off;
        off += ((bytes + 255) & ~(size_t)255);
        return p;
    };
    ushort* xbuf = (ushort*)allocB((size_t)BNR * CC * 2);  // bf16 residual spine
    ushort* ybuf = (ushort*)allocB((size_t)BNR * CC * 2);  // LN out (bf16)
    ushort* wq   = (ushort*)allocB((size_t)AD * AD * 2);
    ushort* wkv1 = (ushort*)allocB((size_t)AD * AD * 2);
    ushort* wkv2 = (ushort*)allocB((size_t)AD * AD * 2);
    ushort* wpr  = (ushort*)allocB((size_t)CC * CC * 2);
    ushort* wf1  = (ushort*)allocB((size_t)HID * CC * 2);
    ushort* wf2  = (ushort*)allocB((size_t)CC * HID * 2);  // f16
    ushort* wcp  = (ushort*)allocB((size_t)64 * 576 * 2);
    float*  lpwt = (float*)allocB((size_t)9 * CC * 4);
    ushort* dwwt = (ushort*)allocB((size_t)9 * HID * 2);   // f16
    size_t zmark = off;                                    // overlay region start
    ushort* cat  = (ushort*)allocB((size_t)BNR * CC * 2);  // [o1|o2|cp] bf16
    ushort* qbuf = (ushort*)allocB((size_t)BNR * AD * 2);
    ushort* x1g  = (ushort*)allocB((size_t)BB * M1 * AD * 2);
    ushort* x2g  = (ushort*)allocB((size_t)BB * M2 * AD * 2);
    ushort* kv1b = (ushort*)allocB((size_t)BB * M1 * AD * 2);  // bf16 kv
    ushort* kv2b = (ushort*)allocB((size_t)BB * M2 * AD * 2);

    int CB2 = 1;
    for (int cb = 16; cb >= 1; cb >>= 1) {
        if (zmark + 2 * (size_t)cb * NN * HID * 2 <= ws_size) { CB2 = cb; break; }
    }

    dim3 b256(256), b512(512), b1024(1024);
    // 0. fused weight prep (one launch)
    wprep_kernel<<<dim3(2925), b256, 0, stream>>>(
        q_w, kv1_w, kv2_w, proj_w, fc1_w, fc2_w, c2_w, lpu_w, dw_w,
        wq, wkv1, wkv2, wpr, wf1, wf2, wcp, lpwt, dwwt);
    // 1. LPU x-walk + residual + fused LN1 (xbuf bf16 + ybuf bf16)
    lpu_kernel<<<dim3(NN / 16, BB), b256, 0, stream>>>(x, lpwt, lpu_b, n1_g, n1_b, xbuf, ybuf);
    // 3. cp branch: MFMA implicit conv + fused LN64+GELU -> cat cols [192,256)
    cpgemm_kernel<<<dim3(BNR / 128), b256, 0, stream>>>(ybuf, wcp, c2_b, cn_g, cn_b, cat);
    // 4. q = ap @ q_w.T  (bf16 out)
    gemm_mfma<4><<<dim3(2, BNR / 256), b512, 0, stream>>>(
        ybuf + CD, CC, wq, AD, AD, nullptr, nullptr, 0, qbuf, AD, BNR);
    // 5. SR convs + LN + GELU
    sr_kernel<8, 7><<<dim3(M1, BB), dim3(192), 0, stream>>>(ybuf + CD, sr1_w, sr1_b, an1_g, an1_b, x1g);
    sr_kernel<4, 14><<<dim3(M2, BB), dim3(192), 0, stream>>>(ybuf + CD, sr2_w, sr2_b, an2_g, an2_b, x2g);
    // 6. kv GEMMs (bf16 out)
    gemm_mfma<4><<<dim3(2, (BB * M1 + 255) / 256), b512, 0, stream>>>(
        x1g, AD, wkv1, AD, AD, nullptr, nullptr, 0, kv1b, AD, BB * M1);
    gemm_mfma<4><<<dim3(2, (BB * M2 + 255) / 256), b512, 0, stream>>>(
        x2g, AD, wkv2, AD, AD, nullptr, nullptr, 0, kv2b, AD, BB * M2);
    // 7. attention (MFMA, 256 q/block) -> cat cols [0,192)
    attn_mfma<M1, 64, 0><<<dim3((NN + 255) / 256, HG, BB), b256, 0, stream>>>(qbuf, kv1b, cat);
    attn_mfma<M2, 224, HG><<<dim3((NN + 255) / 256, HG, BB), b256, 0, stream>>>(qbuf, kv2b, cat);
    // 8. proj + bias + residual + fused LN2 (bf16 spine; writes xbuf AND ybuf)
    projln_kernel<<<dim3(BNR / 128), b512, 0, stream>>>(
        cat, wpr, proj_b, n2_g, n2_b, xbuf, ybuf);
    // 10. MLP (CB2=16 -> single pass); fc1/fc2 use the 16-wave 64KB 2-slot GEMM
    ushort* z1 = (ushort*)(ws + zmark);
    ushort* z2 = z1 + (size_t)CB2 * NN * HID;
    for (int c0 = 0; c0 < BB; c0 += CB2) {
        size_t tokoff = (size_t)c0 * NN;
        int Rr = CB2 * NN;
        gemm_8ph<9><<<dim3(HID / 256, Rr / 256), b1024, 0, stream>>>(
            ybuf + tokoff * CC, CC, wf1, CC, HID, fc1_b, nullptr, 0, z1, HID, Rr);
        dwconv_kernel<<<dim3(HH * 7, CB2), b256, 0, stream>>>(z1, dwwt, dw_b, z2);
        gemm_8ph<3, 1><<<dim3(CC / 256, Rr / 256), b1024, 0, stream>>>(
            z2, HID, wf2, HID, CC, fc2_b, xbuf + tokoff * CC, CC, out + tokoff * CC, CC, Rr);
    }
}

// Round 27
// 346.285 us; speedup vs baseline: 1.0807x; 1.0807x over previous
//
#include <hip/hip_runtime.h>
#include <math.h>

// Problem constants (B=16, H=W=56, C=256)
#define BB   16
#define HH   56
#define WW   56
#define NN   (HH*WW)        // 3136
#define CC   256
#define CD   64
#define AD   192
#define NH   8
#define HG   4
#define HD   24
#define HID  1024
#define M1   49
#define M2   196
#define BNR  (BB*NN)        // 50176

typedef __attribute__((ext_vector_type(8))) short s8v;       // 8 bf16/f16 bit-patterns
typedef __attribute__((ext_vector_type(4))) short s4v;
typedef __attribute__((ext_vector_type(4))) float f4v;
typedef __attribute__((ext_vector_type(8))) _Float16 h8v;    // 8 f16
typedef __attribute__((ext_vector_type(2))) _Float16 h2v;    // 2 f16 (packed math)

// tanh-form GELU; max dev from erf-GELU ~3e-4
__device__ __forceinline__ float gelu_f(float x) {
    float u = x * (1.0f + 0.044715f * x * x);
    float t = __expf(-1.5957691216f * u);
    return x * __builtin_amdgcn_rcpf(1.0f + t);
}
__device__ __forceinline__ ushort f2bf(float f) {
    union { float f; uint32_t u; } c; c.f = f;
    uint32_t u = c.u;
    return (ushort)((u + 0x7fffu + ((u >> 16) & 1u)) >> 16);
}
__device__ __forceinline__ float bf2f(ushort u) {
    union { uint32_t u; float f; } c; c.u = ((uint32_t)u) << 16;
    return c.f;
}
__device__ __forceinline__ ushort f2h(float f) {
    union { _Float16 h; ushort u; } c; c.h = (_Float16)f;
    return c.u;
}
// async global->LDS, 16B per lane; dest = wave-uniform base + lane*16
__device__ __forceinline__ void load_lds16(const void* gsrc, void* ldst) {
    __builtin_amdgcn_global_load_lds(
        (const __attribute__((address_space(1))) void*)gsrc,
        (__attribute__((address_space(3))) void*)ldst, 16, 0, 0);
}
// bijective XCD-chunked block swizzle (m204)
__device__ __forceinline__ int xcd_swz(int bid, int nwg) {
    int q = nwg >> 3, r = nwg & 7;
    int x = bid & 7, i = bid >> 3;
    return (x < r ? x * (q + 1) : r * (q + 1) + (x - r) * q) + i;
}

// ---------------- fused weight prep: all converts/transposes in ONE launch ----------------
__global__ __launch_bounds__(256) void wprep_kernel(
        const float* __restrict__ qw, const float* __restrict__ k1,
        const float* __restrict__ k2, const float* __restrict__ pw,
        const float* __restrict__ f1, const float* __restrict__ f2,
        const float* __restrict__ cw, const float* __restrict__ lw,
        const float* __restrict__ dw,
        ushort* __restrict__ wq, ushort* __restrict__ wkv1,
        ushort* __restrict__ wkv2, ushort* __restrict__ wpr,
        ushort* __restrict__ wf1, ushort* __restrict__ wf2,
        ushort* __restrict__ wcp, float* __restrict__ lpwt,
        ushort* __restrict__ dwwth) {
    int i = blockIdx.x * 256 + threadIdx.x;
    if (i < 36864) { wq[i] = f2bf(qw[i]); return; } i -= 36864;
    if (i < 36864) { wkv1[i] = f2bf(k1[i]); return; } i -= 36864;
    if (i < 36864) { wkv2[i] = f2bf(k2[i]); return; } i -= 36864;
    if (i < 65536) { wpr[i] = f2bf(pw[i]); return; } i -= 65536;
    if (i < 262144) { wf1[i] = f2bf(f1[i]); return; } i -= 262144;
    if (i < 262144) { wf2[i] = f2h(f2[i]); return; } i -= 262144;
    if (i < 36864) {
        int co = i / 576, k = i - co * 576;
        int tap = k >> 6, ci = k & 63;
        wcp[i] = f2bf(cw[co * 576 + ci * 9 + tap]);
        return;
    } i -= 36864;
    if (i < 2304) { int c = i / 9, t = i - c * 9; lpwt[t * CC + c] = lw[i]; return; } i -= 2304;
    if (i < 9216) { int c = i / 9, t = i - c * 9; dwwth[t * HID + c] = f2h(dw[i]); }
}

// ---------------- LPU x-walk: dw3x3 + bias + residual + fused LN1; 4 px/wave ----------------
__global__ __launch_bounds__(256) void lpu_kernel(const float* __restrict__ x,
        const float* __restrict__ wt, const float* __restrict__ bias,
        const float* __restrict__ n1g, const float* __restrict__ n1b,
        ushort* __restrict__ xbuf, ushort* __restrict__ ybuf) {
    int tid = threadIdx.x;
    int lane = tid & 63, wv = tid >> 6;
    int c = lane * 4;
    int grp = xcd_swz(blockIdx.x, NN / 16) * 4 + wv;
    int n0 = grp * 4;
    int h = n0 / WW, x0 = n0 - h * WW;
    int b = blockIdx.y;
    const float* xb = x + (size_t)b * NN * CC + c;
    float4 wreg[9];
#pragma unroll
    for (int t = 0; t < 9; ++t) wreg[t] = *(const float4*)(wt + t * CC + c);
    float4 bz = *(const float4*)(bias + c);
    float4 acc[4] = {bz, bz, bz, bz};
#pragma unroll
    for (int cx = 0; cx < 6; ++cx) {
        int wx = x0 + cx - 1;
        if ((unsigned)wx >= (unsigned)WW) continue;
#pragma unroll
        for (int ky = 0; ky < 3; ++ky) {
            int hy = h + ky - 1;
            if ((unsigned)hy >= (unsigned)HH) continue;
            float4 xv = *(const float4*)(xb + (size_t)(hy * WW + wx) * CC);
#pragma unroll
            for (int xo = 0; xo < 4; ++xo) {
                int kx = cx - xo;
                if (kx < 0 || kx > 2) continue;
                float4 wv4 = wreg[ky * 3 + kx];
                acc[xo].x = fmaf(xv.x, wv4.x, acc[xo].x);
                acc[xo].y = fmaf(xv.y, wv4.y, acc[xo].y);
                acc[xo].z = fmaf(xv.z, wv4.z, acc[xo].z);
                acc[xo].w = fmaf(xv.w, wv4.w, acc[xo].w);
            }
        }
    }
    float4 gv = *(const float4*)(n1g + c);
    float4 bv = *(const float4*)(n1b + c);
#pragma unroll
    for (int xo = 0; xo < 4; ++xo) {
        size_t o = ((size_t)b * NN + n0 + xo) * CC + c;
        float4 rv = *(const float4*)(x + o);
        float4 a = acc[xo];
        a.x += rv.x; a.y += rv.y; a.z += rv.z; a.w += rv.w;
        s4v xv4;
        xv4.x = (short)f2bf(a.x);
        xv4.y = (short)f2bf(a.y);
        xv4.z = (short)f2bf(a.z);
        xv4.w = (short)f2bf(a.w);
        *(s4v*)(xbuf + o) = xv4;
        float s = a.x + a.y + a.z + a.w;
        float sq = a.x * a.x + a.y * a.y + a.z * a.z + a.w * a.w;
#pragma unroll
        for (int off = 32; off >= 1; off >>= 1) {
            s += __shfl_xor(s, off, 64);
            sq += __shfl_xor(sq, off, 64);
        }
        float mean = s * (1.0f / 256.0f);
        float var = sq * (1.0f / 256.0f) - mean * mean;
        float rstd = rsqrtf(var + 1e-5f);
        s4v ov;
        ov.x = (short)f2bf((a.x - mean) * rstd * gv.x + bv.x);
        ov.y = (short)f2bf((a.y - mean) * rstd * gv.y + bv.y);
        ov.z = (short)f2bf((a.z - mean) * rstd * gv.z + bv.z);
        ov.w = (short)f2bf((a.w - mean) * rstd * gv.w + bv.w);
        *(s4v*)(ybuf + o) = ov;
    }
}

// ---------------- cp branch: implicit-GEMM conv + fused LN(64)+GELU epilogue ----------------
__global__ __launch_bounds__(256) void cpgemm_kernel(
        const ushort* __restrict__ y, const ushort* __restrict__ wt,
        const float* __restrict__ cb, const float* __restrict__ cng,
        const float* __restrict__ cnb, ushort* __restrict__ cat) {
    __shared__ __align__(16) ushort As[128 * 32];
    __shared__ __align__(16) ushort Ws[64 * 32];
    int tid = threadIdx.x;
    int wid = tid >> 6, lane = tid & 63;
    int rt = xcd_swz(blockIdx.x, BNR / 128) * 128;
    int r0 = tid >> 2, c0 = tid & 3;
    int r1 = r0 + 64;
    int tok0 = rt + r0, tok1 = rt + r1;
    int b0 = tok0 / NN, n0 = tok0 - b0 * NN, h0 = n0 / WW, w0 = n0 - h0 * WW;
    int b1 = tok1 / NN, n1 = tok1 - b1 * NN, h1 = n1 / WW, w1 = n1 - h1 * WW;
    const ushort* Wp = wt + (size_t)r0 * 576 + c0 * 8;
    int aw0 = (c0 ^ (r0 & 3)) << 3;
    f4v acc[2][4];
#pragma unroll
    for (int m = 0; m < 2; ++m)
#pragma unroll
        for (int n = 0; n < 4; ++n) acc[m][n] = (f4v)0.f;
    int lr = lane & 15, g4 = lane >> 4;
    int swz = (g4 ^ (lr & 3)) << 3;
    for (int kt = 0; kt < 576; kt += 32) {
        int tap = kt >> 6, ci0 = kt & 63;
        int t3 = tap / 3, dy = t3 - 1, dx = (tap - t3 * 3) - 1;
        s8v a0 = (s8v)0, a1 = (s8v)0;
        int hy0 = h0 + dy, wx0 = w0 + dx;
        if ((unsigned)hy0 < (unsigned)HH && (unsigned)wx0 < (unsigned)WW)
            a0 = *(const s8v*)(y + ((size_t)b0 * NN + hy0 * WW + wx0) * CC + ci0 + c0 * 8);
        int hy1 = h1 + dy, wx1 = w1 + dx;
        if ((unsigned)hy1 < (unsigned)HH && (unsigned)wx1 < (unsigned)WW)
            a1 = *(const s8v*)(y + ((size_t)b1 * NN + hy1 * WW + wx1) * CC + ci0 + c0 * 8);
        s8v wv = *(const s8v*)(Wp + kt);
        __syncthreads();
        *(s8v*)&As[r0 * 32 + aw0] = a0;
        *(s8v*)&As[r1 * 32 + aw0] = a1;
        *(s8v*)&Ws[r0 * 32 + aw0] = wv;
        __syncthreads();
        s8v af[2], bf[4];
#pragma unroll
        for (int m = 0; m < 2; ++m)
            af[m] = *(const s8v*)&As[(wid * 32 + m * 16 + lr) * 32 + swz];
#pragma unroll
        for (int n = 0; n < 4; ++n)
            bf[n] = *(const s8v*)&Ws[(n * 16 + lr) * 32 + swz];
#pragma unroll
        for (int m = 0; m < 2; ++m)
#pragma unroll
            for (int n = 0; n < 4; ++n)
                acc[m][n] = __builtin_amdgcn_mfma_f32_16x16x32_bf16(af[m], bf[n], acc[m][n], 0, 0, 0);
    }
    float gv[4], bv[4], cbv[4];
#pragma unroll
    for (int n = 0; n < 4; ++n) {
        int gc = n * 16 + lr;
        cbv[n] = cb[gc];
        gv[n] = cng[gc];
        bv[n] = cnb[gc];
    }
#pragma unroll
    for (int m = 0; m < 2; ++m)
#pragma unroll
        for (int r = 0; r < 4; ++r) {
            float s = 0.f, sq = 0.f;
#pragma unroll
            for (int n = 0; n < 4; ++n) {
                float v = acc[m][n][r] + cbv[n];
                acc[m][n][r] = v;
                s += v; sq += v * v;
            }
#pragma unroll
            for (int off = 1; off < 16; off <<= 1) {
                s += __shfl_xor(s, off, 64);
                sq += __shfl_xor(sq, off, 64);
            }
            float mean = s * (1.0f / 64.0f);
            float var = sq * (1.0f / 64.0f) - mean * mean;
            float rstd = rsqrtf(var + 1e-5f);
            int row = rt + wid * 32 + m * 16 + g4 * 4 + r;
            ushort* op = cat + (size_t)row * CC + 192;
#pragma unroll
            for (int n = 0; n < 4; ++n) {
                float v = (acc[m][n][r] - mean) * rstd * gv[n] + bv[n];
                op[n * 16 + lr] = f2bf(gelu_f(v));
            }
        }
}

// ---------------- SR conv (depthwise KSxKS stride KS) + LN(192) + GELU, bf16 io ----------------
template <int KS, int OW>
__global__ __launch_bounds__(192) void sr_kernel(const ushort* __restrict__ yap,
        const float* __restrict__ w, const float* __restrict__ bias,
        const float* __restrict__ g, const float* __restrict__ bt,
        ushort* __restrict__ out) {
    int ch = threadIdx.x;
    int m = blockIdx.x, b = blockIdx.y;
    int oh = m / OW, ow = m - oh * OW;
    const ushort* yb = yap + (size_t)b * NN * CC;
    float acc = bias[ch];
#pragma unroll
    for (int ky = 0; ky < KS; ++ky)
#pragma unroll
        for (int kx = 0; kx < KS; ++kx)
            acc = fmaf(bf2f(yb[(size_t)((oh * KS + ky) * WW + ow * KS + kx) * CC + ch]),
                       w[ch * KS * KS + ky * KS + kx], acc);
    __shared__ float red[2][3];
    float s = acc, sq = acc * acc;
#pragma unroll
    for (int off = 32; off >= 1; off >>= 1) {
        s += __shfl_xor(s, off, 64);
        sq += __shfl_xor(sq, off, 64);
    }
    int wv = threadIdx.x >> 6, lane = threadIdx.x & 63;
    if (lane == 0) { red[0][wv] = s; red[1][wv] = sq; }
    __syncthreads();
    s = red[0][0] + red[0][1] + red[0][2];
    sq = red[1][0] + red[1][1] + red[1][2];
    float mean = s * (1.0f / 192.0f);
    float var = sq * (1.0f / 192.0f) - mean * mean;
    float rstd = rsqrtf(var + 1e-5f);
    float v = (acc - mean) * rstd * g[ch] + bt[ch];
    out[((size_t)b * (OW * OW) + m) * AD + ch] = f2bf(gelu_f(v));
}

// ---------------- MFMA GEMM: 256x128 tile, 512 thr / 8 waves, 2-phase (q/kv) ----------------
// MODE bits: 1=bias(fp32), 2=residual(bf16, stride ldr), 4=output bf16, 8=output f16 (else fp32)
template <int MODE, int F16 = 0>
__global__ __launch_bounds__(512) void gemm_mfma(
        const ushort* __restrict__ A, int lda,
        const ushort* __restrict__ W, int K, int O,
        const float* __restrict__ bias,
        const ushort* __restrict__ res, int ldr,
        void* __restrict__ Cout, int ldc, int R) {
    __shared__ __align__(16) ushort As[2 * 256 * 32];   // 32KB
    __shared__ __align__(16) ushort Ws[2 * 128 * 32];   // 16KB
    int tid = threadIdx.x;
    int w8 = tid >> 6, lane = tid & 63;
    int wr = w8 >> 1, wc = w8 & 1;
    int nwg = gridDim.x * gridDim.y;
    int swzb = xcd_swz(blockIdx.y * gridDim.x + blockIdx.x, nwg);
    int rt = (swzb / gridDim.x) * 256, ot = (swzb % gridDim.x) * 128;
    int r0 = tid >> 2, cslot = tid & 3;
    int csrc = (cslot ^ (r0 & 3)) * 8;
    const ushort* Ap0 = A + (size_t)min(rt + r0, R - 1) * lda + csrc;
    const ushort* Ap1 = A + (size_t)min(rt + r0 + 128, R - 1) * lda + csrc;
    const ushort* Wp0 = W + (size_t)min(ot + r0, O - 1) * K + csrc;
    char* lA0 = (char*)As + w8 * 1024;
    char* lA1 = (char*)As + 8192 + w8 * 1024;
    char* lW0 = (char*)Ws + w8 * 1024;
    f4v acc[4][4];
#pragma unroll
    for (int m = 0; m < 4; ++m)
#pragma unroll
        for (int n = 0; n < 4; ++n) acc[m][n] = (f4v)0.f;
    int lr = lane & 15;
    int swz = ((lane >> 4) ^ (lr & 3)) << 3;
    load_lds16(Ap0, lA0);
    load_lds16(Ap1, lA1);
    load_lds16(Wp0, lW0);
    __syncthreads();
    int cur = 0;
    for (int kt = 0; kt < K; kt += 32) {
        if (kt + 32 < K) {
            int pa = (cur ^ 1) * 16384, pw = (cur ^ 1) * 8192;
            load_lds16(Ap0 + kt + 32, lA0 + pa);
            load_lds16(Ap1 + kt + 32, lA1 + pa);
            load_lds16(Wp0 + kt + 32, lW0 + pw);
        }
        const ushort* Ab = As + cur * 8192;
        const ushort* Wb = Ws + cur * 4096;
        s8v af[4], bf[4];
#pragma unroll
        for (int m = 0; m < 4; ++m)
            af[m] = *(const s8v*)&Ab[(wr * 64 + m * 16 + lr) * 32 + swz];
#pragma unroll
        for (int n = 0; n < 4; ++n)
            bf[n] = *(const s8v*)&Wb[(wc * 64 + n * 16 + lr) * 32 + swz];
#pragma unroll
        for (int m = 0; m < 4; ++m)
#pragma unroll
            for (int n = 0; n < 4; ++n) {
                if (F16) {
                    h8v ah = *(const h8v*)&af[m];
                    h8v bh = *(const h8v*)&bf[n];
                    acc[m][n] = __builtin_amdgcn_mfma_f32_16x16x32_f16(ah, bh, acc[m][n], 0, 0, 0);
                } else {
                    acc[m][n] = __builtin_amdgcn_mfma_f32_16x16x32_bf16(af[m], bf[n], acc[m][n], 0, 0, 0);
                }
            }
        __syncthreads();
        cur ^= 1;
    }
#pragma unroll
    for (int m = 0; m < 4; ++m)
#pragma unroll
        for (int n = 0; n < 4; ++n) {
            int gr = rt + wr * 64 + m * 16 + (lane >> 4) * 4;
            int gc = ot + wc * 64 + n * 16 + (lane & 15);
            if (gc >= O) continue;
#pragma unroll
            for (int r = 0; r < 4; ++r) {
                int row = gr + r;
                if (row >= R) continue;
                float v = acc[m][n][r];
                if (MODE & 1) v += bias[gc];
                if (MODE & 2) v += bf2f(res[(size_t)row * ldr + gc]);
                if (MODE & 4)      ((ushort*)Cout)[(size_t)row * ldc + gc] = f2bf(v);
                else if (MODE & 8) ((ushort*)Cout)[(size_t)row * ldc + gc] = f2h(v);
                else               ((float*)Cout)[(size_t)row * ldc + gc] = v;
            }
        }
}

// ---------------- 16-wave 8-phase GEMM: 256x256 tile, BK=64, counted vmcnt, depth-3 ----------------
// (R25 best-measured: 1024 thr / 16 waves (4x4), wave 64x64 out, 128KB LDS, vmcnt(4) steady)
template <int MODE, int F16 = 0>
__global__ __launch_bounds__(1024) void gemm_8ph(
        const ushort* __restrict__ A, int lda,
        const ushort* __restrict__ W, int K, int O,
        const float* __restrict__ bias,
        const ushort* __restrict__ res, int ldr,
        void* __restrict__ Cout, int ldc, int R) {
    __shared__ __align__(16) ushort Al[2 * 256 * 64];   // 64KB
    __shared__ __align__(16) ushort Wl[2 * 256 * 64];   // 64KB
    int tid = threadIdx.x;
    int w16 = tid >> 6, lane = tid & 63;
    int wr = w16 >> 2, wc = w16 & 3;          // 4 x 4 wave grid
    int nwg = gridDim.x * gridDim.y;
    int swzb = xcd_swz(blockIdx.y * gridDim.x + blockIdx.x, nwg);
    int rt = (swzb / gridDim.x) * 256, ot = (swzb % gridDim.x) * 256;
    int lr = lane & 15, g4 = lane >> 4;
    int swz = (g4 ^ (lr & 3)) << 3;
    int ar0 = tid >> 2, sp0 = tid & 3;        // 1024 units cover all 256 rows x 4 slots
    int cs0 = ((sp0 ^ (ar0 & 3)) << 3);       // inverse-swizzled source K-slot
    const ushort* Ap0 = A + (size_t)(rt + ar0) * lda + cs0;
    const ushort* Wp0 = W + (size_t)(ot + ar0) * K + cs0;
    int d0 = w16 * 1024;                       // LDS dest byte offset (lane*16 implicit)
    f4v acc[4][4];
#pragma unroll
    for (int m = 0; m < 4; ++m)
#pragma unroll
        for (int n = 0; n < 4; ++n)
            acc[m][n] = (f4v)((MODE & 1) ? bias[ot + wc * 64 + n * 16 + lr] : 0.0f);
    auto STAGE = [&](int s) {
        int t = s >> 1, hf = s & 1;
        int boff = (t & 1) * 32768 + hf * 16384;   // byte offset in each LDS array
        int kc = t * 64 + hf * 32;
        load_lds16(Ap0 + kc, (char*)Al + boff + d0);
        load_lds16(Wp0 + kc, (char*)Wl + boff + d0);
    };
    int nS = K >> 5;                           // half-stages (32-K each)
    STAGE(0); STAGE(1); STAGE(2);
    for (int s = 0; s < nS; ++s) {
        if (s < nS - 2)       asm volatile("s_waitcnt vmcnt(4)" ::: "memory");
        else if (s == nS - 2) asm volatile("s_waitcnt vmcnt(2)" ::: "memory");
        else                  asm volatile("s_waitcnt vmcnt(0)" ::: "memory");
        __builtin_amdgcn_s_barrier();
        __builtin_amdgcn_sched_barrier(0);
        if (s + 3 < nS) STAGE(s + 3);
        int uoff = ((s >> 1) & 1) * 16384 + (s & 1) * 8192;   // ushort index offset
        const ushort* Ab = Al + uoff;
        const ushort* Wb = Wl + uoff;
        s8v af[4], bf[4];
#pragma unroll
        for (int m = 0; m < 4; ++m)
            af[m] = *(const s8v*)&Ab[(wr * 64 + m * 16 + lr) * 32 + swz];
#pragma unroll
        for (int n = 0; n < 4; ++n)
            bf[n] = *(const s8v*)&Wb[(wc * 64 + n * 16 + lr) * 32 + swz];
        __builtin_amdgcn_s_setprio(1);
#pragma unroll
        for (int m = 0; m < 4; ++m)
#pragma unroll
            for (int n = 0; n < 4; ++n) {
                if (F16) {
                    h8v ah = *(const h8v*)&af[m];
                    h8v bh = *(const h8v*)&bf[n];
                    acc[m][n] = __builtin_amdgcn_mfma_f32_16x16x32_f16(ah, bh, acc[m][n], 0, 0, 0);
                } else {
                    acc[m][n] = __builtin_amdgcn_mfma_f32_16x16x32_bf16(af[m], bf[n], acc[m][n], 0, 0, 0);
                }
            }
        __builtin_amdgcn_s_setprio(0);
    }
#pragma unroll
    for (int m = 0; m < 4; ++m) {
        int gr = rt + wr * 64 + m * 16 + g4 * 4;
#pragma unroll
        for (int n = 0; n < 4; ++n) {
            int gc = ot + wc * 64 + n * 16 + lr;
#pragma unroll
            for (int r = 0; r < 4; ++r) {
                int row = gr + r;
                float v = acc[m][n][r];
                if (MODE & 2) v += bf2f(res[(size_t)row * ldr + gc]);
                if (MODE & 4)      ((ushort*)Cout)[(size_t)row * ldc + gc] = f2bf(v);
                else if (MODE & 8) ((ushort*)Cout)[(size_t)row * ldc + gc] = f2h(v);
                else               ((float*)Cout)[(size_t)row * ldc + gc] = v;
            }
        }
    }
}

// ---------------- proj (O=256) + bias + residual + fused LN2 ----------------
__global__ __launch_bounds__(512) void projln_kernel(
        const ushort* __restrict__ A, const ushort* __restrict__ W,
        const float* __restrict__ bias,
        const float* __restrict__ n2g, const float* __restrict__ n2b,
        ushort* __restrict__ xbuf, ushort* __restrict__ ybuf) {
    __shared__ __align__(16) ushort As[128 * 32];   // 8KB
    __shared__ __align__(16) ushort Ws[256 * 32];   // 16KB
    int tid = threadIdx.x;
    int w8 = tid >> 6, lane = tid & 63;
    int rt = xcd_swz(blockIdx.x, BNR / 128) * 128;
    int r0 = tid >> 2, cslot = tid & 3;
    int csrc = (cslot ^ (r0 & 3)) * 8;
    const ushort* Ap0 = A + (size_t)(rt + r0) * CC + csrc;
    const ushort* Wp0 = W + (size_t)r0 * CC + csrc;
    const ushort* Wp1 = W + (size_t)(r0 + 128) * CC + csrc;
    char* lA0 = (char*)As + w8 * 1024;
    char* lW0 = (char*)Ws + w8 * 1024;
    char* lW1 = (char*)Ws + 8192 + w8 * 1024;
    int lr = lane & 15, g4 = lane >> 4;
    int swz = (g4 ^ (lr & 3)) << 3;
    f4v acc[16];
#pragma unroll
    for (int n = 0; n < 16; ++n) acc[n] = (f4v)(bias[n * 16 + lr]);
    for (int kt = 0; kt < CC; kt += 32) {
        __syncthreads();
        load_lds16(Ap0 + kt, lA0);
        load_lds16(Wp0 + kt, lW0);
        load_lds16(Wp1 + kt, lW1);
        __syncthreads();
        s8v af = *(const s8v*)&As[(w8 * 16 + lr) * 32 + swz];
#pragma unroll
        for (int n = 0; n < 16; ++n) {
            s8v bf = *(const s8v*)&Ws[(n * 16 + lr) * 32 + swz];
            acc[n] = __builtin_amdgcn_mfma_f32_16x16x32_bf16(af, bf, acc[n], 0, 0, 0);
        }
    }
#pragma unroll
    for (int r = 0; r < 4; ++r) {
        int row = rt + w8 * 16 + g4 * 4 + r;
        ushort* xr = xbuf + (size_t)row * CC;
        ushort* yr = ybuf + (size_t)row * CC;
        float s = 0.f, sq = 0.f;
#pragma unroll
        for (int n = 0; n < 16; ++n) {
            float v = acc[n][r] + bf2f(xr[n * 16 + lr]);
            acc[n][r] = v;
            s += v; sq += v * v;
        }
#pragma unroll
        for (int off = 1; off < 16; off <<= 1) {
            s += __shfl_xor(s, off, 64);
            sq += __shfl_xor(sq, off, 64);
        }
        float mean = s * (1.0f / 256.0f);
        float var = sq * (1.0f / 256.0f) - mean * mean;
        float rstd = rsqrtf(var + 1e-5f);
#pragma unroll
        for (int n = 0; n < 16; ++n) {
            int col = n * 16 + lr;
            float v = acc[n][r];
            xr[col] = f2bf(v);
            yr[col] = f2bf((v - mean) * rstd * n2g[col] + n2b[col]);
        }
    }
}

// ---------------- MFMA attention body (shared by both K/V groups) ----------------
template <int M, int MP>
__device__ __forceinline__ void attn_body(const ushort* __restrict__ q,
        const ushort* __restrict__ kvb, ushort* __restrict__ cat,
        ushort* Kl, ushort* VT, int g, int h, int b) {
    constexpr int NT = MP / 16;
    constexpr int NCH = MP / 32;
    int tid = threadIdx.x;
    for (int i = tid; i < MP * 4; i += 256) ((s8v*)Kl)[i] = (s8v)0;
    for (int i = tid; i < MP * 4; i += 256) ((s8v*)VT)[i] = (s8v)0;
    __syncthreads();
    for (int u = tid; u < M * 3; u += 256) {
        int m = u / 3, d0 = u - m * 3;
        s8v kv8 = *(const s8v*)(kvb + ((size_t)b * M + m) * AD + g * HD + d0 * 8);
        *(s8v*)&Kl[m * 32 + ((d0 ^ (m & 3)) << 3)] = kv8;
    }
    for (int u = tid; u < M * 3; u += 256) {
        int m = u / 3, d0 = u - m * 3;
        s8v vv = *(const s8v*)(kvb + ((size_t)b * M + m) * AD + 96 + g * HD + d0 * 8);
        int c = m >> 5, mm = m & 31;
        int gg = (mm >> 2) & 3;
        int t = (mm & 3) + ((mm & 16) >> 2);
#pragma unroll
        for (int j = 0; j < 8; ++j) {
            int d = d0 * 8 + j;
            VT[d * MP + ((c * 4 + (gg ^ (d & 3))) << 3) + t] = (ushort)vv[j];
        }
    }
    __syncthreads();
    int w = tid >> 6, lane = tid & 63;
    int ln = lane & 15, g4 = lane >> 4;
    int swz = (g4 ^ (ln & 3)) << 3;
    const float scale = 0.20412414523193154f;  // 24^-0.5
    for (int nt = 0; nt < 4; ++nt) {
        int nbase = blockIdx.x * 256 + nt * 64;
        if (nbase >= NN) break;
        int n0 = nbase + w * 16 + ln;
        s8v qf = (s8v)0;
        if (g4 < 3) qf = *(const s8v*)(q + ((size_t)b * NN + n0) * AD + h * HD + g4 * 8);
        f4v sa[NT];
#pragma unroll
        for (int t = 0; t < NT; ++t) sa[t] = (f4v)0.f;
#pragma unroll
        for (int t = 0; t < NT; ++t) {
            s8v kf = *(const s8v*)&Kl[(t * 16 + ln) * 32 + swz];
            sa[t] = __builtin_amdgcn_mfma_f32_16x16x32_bf16(kf, qf, sa[t], 0, 0, 0);
        }
        float mx = -3.0e38f;
#pragma unroll
        for (int t = 0; t < NT; ++t)
#pragma unroll
            for (int r = 0; r < 4; ++r) {
                int m = t * 16 + g4 * 4 + r;
                float v = (m < M) ? sa[t][r] * scale : -3.0e38f;
                sa[t][r] = v;
                mx = fmaxf(mx, v);
            }
        mx = fmaxf(mx, __shfl_xor(mx, 16, 64));
        mx = fmaxf(mx, __shfl_xor(mx, 32, 64));
        float sum = 0.f;
#pragma unroll
        for (int t = 0; t < NT; ++t)
#pragma unroll
            for (int r = 0; r < 4; ++r) {
                float p = __expf(sa[t][r] - mx);
                sa[t][r] = p;
                sum += p;
            }
        sum += __shfl_xor(sum, 16, 64);
        sum += __shfl_xor(sum, 32, 64);
        float inv = 1.0f / sum;
        f4v oa[2] = {(f4v)0.f, (f4v)0.f};
#pragma unroll
        for (int c = 0; c < NCH; ++c) {
            s8v pb;
#pragma unroll
            for (int t = 0; t < 4; ++t) {
                pb[t]     = (short)f2bf(sa[c * 2][t]);
                pb[4 + t] = (short)f2bf(sa[c * 2 + 1][t]);
            }
#pragma unroll
            for (int dt = 0; dt < 2; ++dt) {
                s8v vf = *(const s8v*)&VT[(dt * 16 + ln) * MP + c * 32 + swz];
                oa[dt] = __builtin_amdgcn_mfma_f32_16x16x32_bf16(vf, pb, oa[dt], 0, 0, 0);
            }
        }
        ushort* op = cat + ((size_t)b * NN + n0) * CC + h * HD;
        s4v o0;
#pragma unroll
        for (int r = 0; r < 4; ++r) o0[r] = (short)f2bf(oa[0][r] * inv);
        *(s4v*)(op + g4 * 4) = o0;
        if (g4 < 2) {
            s4v o1;
#pragma unroll
            for (int r = 0; r < 4; ++r) o1[r] = (short)f2bf(oa[1][r] * inv);
            *(s4v*)(op + 16 + g4 * 4) = o1;
        }
    }
}

// merged attention: blockIdx.y in [0,8) covers both K/V groups in ONE dispatch
__global__ __launch_bounds__(256) void attn_both(const ushort* __restrict__ q,
        const ushort* __restrict__ kv1b, const ushort* __restrict__ kv2b,
        ushort* __restrict__ cat) {
    __shared__ __align__(16) ushort Kl[224 * 32];
    __shared__ __align__(16) ushort VT[32 * 224];
    int hy = blockIdx.y, b = blockIdx.z;
    if (hy < HG) attn_body<M1, 64>(q, kv1b, cat, Kl, VT, hy, hy, b);
    else         attn_body<M2, 224>(q, kv2b, cat, Kl, VT, hy - HG, hy, b);
}

// ---------------- depthwise 3x3 hid=1024: x-walk, f16 packed math ----------------
__global__ __launch_bounds__(256) void dwconv_kernel(const ushort* __restrict__ z1,
        const ushort* __restrict__ wt, const float* __restrict__ bias,
        ushort* __restrict__ z2) {
    int bid = xcd_swz(blockIdx.x, HH * 7);
    int h = bid / 7, bx = bid - h * 7;
    int b = blockIdx.y;
    int c = (threadIdx.x & 127) * 8;
    int x0 = bx * 8 + (threadIdx.x >> 7) * 4;
    const ushort* zrow = z1 + ((size_t)b * NN + h * WW) * HID + c;
    h2v wreg[9][4];
#pragma unroll
    for (int t = 0; t < 9; ++t) {
        s8v w8 = *(const s8v*)(wt + t * HID + c);
        const h2v* wp = (const h2v*)&w8;
#pragma unroll
        for (int p = 0; p < 4; ++p) wreg[t][p] = wp[p];
    }
    h2v acc[4][4];
    {
        float4 b0 = *(const float4*)(bias + c);
        float4 b1 = *(const float4*)(bias + c + 4);
        h2v bz[4];
        bz[0][0] = (_Float16)b0.x; bz[0][1] = (_Float16)b0.y;
        bz[1][0] = (_Float16)b0.z; bz[1][1] = (_Float16)b0.w;
        bz[2][0] = (_Float16)b1.x; bz[2][1] = (_Float16)b1.y;
        bz[3][0] = (_Float16)b1.z; bz[3][1] = (_Float16)b1.w;
#pragma unroll
        for (int xo = 0; xo < 4; ++xo)
#pragma unroll
            for (int p = 0; p < 4; ++p) acc[xo][p] = bz[p];
    }
#pragma unroll
    for (int cx = 0; cx < 6; ++cx) {
        int wx = x0 + cx - 1;
        if ((unsigned)wx >= (unsigned)WW) continue;
#pragma unroll
        for (int ky = 0; ky < 3; ++ky) {
            int hy = h + ky - 1;
            if ((unsigned)hy >= (unsigned)HH) continue;
            s8v v = *(const s8v*)(zrow + ((size_t)(ky - 1) * WW + wx) * HID);
            const h2v* v2 = (const h2v*)&v;
#pragma unroll
            for (int xo = 0; xo < 4; ++xo) {
                int kx = cx - xo;
                if (kx < 0 || kx > 2) continue;
#pragma unroll
                for (int p = 0; p < 4; ++p)
                    acc[xo][p] = v2[p] * wreg[ky * 3 + kx][p] + acc[xo][p];
            }
        }
    }
    ushort* zo = z2 + ((size_t)b * NN + h * WW + x0) * HID + c;
#pragma unroll
    for (int xo = 0; xo < 4; ++xo) {
        s8v o;
#pragma unroll
        for (int p = 0; p < 4; ++p) {
            o[p * 2]     = (short)f2h(gelu_f((float)acc[xo][p][0]));
            o[p * 2 + 1] = (short)f2h(gelu_f((float)acc[xo][p][1]));
        }
        *(s8v*)(zo + (size_t)xo * HID) = o;
    }
}

extern "C" void kernel_launch(void* const* d_in, const int* in_sizes, int n_in,
                              void* d_out, int out_size, void* d_ws, size_t ws_size,
                              hipStream_t stream) {
    const float* x      = (const float*)d_in[0];
    const float* lpu_w  = (const float*)d_in[3];
    const float* lpu_b  = (const float*)d_in[4];
    const float* n1_g   = (const float*)d_in[5];
    const float* n1_b   = (const float*)d_in[6];
    const float* c2_w   = (const float*)d_in[7];
    const float* c2_b   = (const float*)d_in[8];
    const float* cn_g   = (const float*)d_in[9];
    const float* cn_b   = (const float*)d_in[10];
    const float* q_w    = (const float*)d_in[11];
    const float* sr1_w  = (const float*)d_in[12];
    const float* sr1_b  = (const float*)d_in[13];
    const float* an1_g  = (const float*)d_in[14];
    const float* an1_b  = (const float*)d_in[15];
    const float* sr2_w  = (const float*)d_in[16];
    const float* sr2_b  = (const float*)d_in[17];
    const float* an2_g  = (const float*)d_in[18];
    const float* an2_b  = (const float*)d_in[19];
    const float* kv1_w  = (const float*)d_in[20];
    const float* kv2_w  = (const float*)d_in[21];
    const float* proj_w = (const float*)d_in[22];
    const float* proj_b = (const float*)d_in[23];
    const float* n2_g   = (const float*)d_in[24];
    const float* n2_b   = (const float*)d_in[25];
    const float* fc1_w  = (const float*)d_in[26];
    const float* fc1_b  = (const float*)d_in[27];
    const float* dw_w   = (const float*)d_in[28];
    const float* dw_b   = (const float*)d_in[29];
    const float* fc2_w  = (const float*)d_in[30];
    const float* fc2_b  = (const float*)d_in[31];
    float* out = (float*)d_out;

    char* ws = (char*)d_ws;
    size_t off = 0;
    auto allocB = [&](size_t bytes) {
        char* p = ws + off;
        off += ((bytes + 255) & ~(size_t)255);
        return p;
    };
    ushort* xbuf = (ushort*)allocB((size_t)BNR * CC * 2);  // bf16 residual spine
    ushort* ybuf = (ushort*)allocB((size_t)BNR * CC * 2);  // LN out (bf16)
    ushort* wq   = (ushort*)allocB((size_t)AD * AD * 2);
    ushort* wkv1 = (ushort*)allocB((size_t)AD * AD * 2);
    ushort* wkv2 = (ushort*)allocB((size_t)AD * AD * 2);
    ushort* wpr  = (ushort*)allocB((size_t)CC * CC * 2);
    ushort* wf1  = (ushort*)allocB((size_t)HID * CC * 2);
    ushort* wf2  = (ushort*)allocB((size_t)CC * HID * 2);  // f16
    ushort* wcp  = (ushort*)allocB((size_t)64 * 576 * 2);
    float*  lpwt = (float*)allocB((size_t)9 * CC * 4);
    ushort* dwwt = (ushort*)allocB((size_t)9 * HID * 2);   // f16
    size_t zmark = off;                                    // overlay region start
    ushort* cat  = (ushort*)allocB((size_t)BNR * CC * 2);  // [o1|o2|cp] bf16
    ushort* qbuf = (ushort*)allocB((size_t)BNR * AD * 2);
    ushort* x1g  = (ushort*)allocB((size_t)BB * M1 * AD * 2);
    ushort* x2g  = (ushort*)allocB((size_t)BB * M2 * AD * 2);
    ushort* kv1b = (ushort*)allocB((size_t)BB * M1 * AD * 2);  // bf16 kv
    ushort* kv2b = (ushort*)allocB((size_t)BB * M2 * AD * 2);

    int CB2 = 1;
    for (int cb = 16; cb >= 1; cb >>= 1) {
        if (zmark + 2 * (size_t)cb * NN * HID * 2 <= ws_size) { CB2 = cb; break; }
    }

    dim3 b256(256), b512(512), b1024(1024);
    // 0. fused weight prep (one launch)
    wprep_kernel<<<dim3(2925), b256, 0, stream>>>(
        q_w, kv1_w, kv2_w, proj_w, fc1_w, fc2_w, c2_w, lpu_w, dw_w,
        wq, wkv1, wkv2, wpr, wf1, wf2, wcp, lpwt, dwwt);
    // 1. LPU x-walk + residual + fused LN1 (xbuf bf16 + ybuf bf16)
    lpu_kernel<<<dim3(NN / 16, BB), b256, 0, stream>>>(x, lpwt, lpu_b, n1_g, n1_b, xbuf, ybuf);
    // 3. cp branch: MFMA implicit conv + fused LN64+GELU -> cat cols [192,256)
    cpgemm_kernel<<<dim3(BNR / 128), b256, 0, stream>>>(ybuf, wcp, c2_b, cn_g, cn_b, cat);
    // 4. q = ap @ q_w.T  (bf16 out)
    gemm_mfma<4><<<dim3(2, BNR / 256), b512, 0, stream>>>(
        ybuf + CD, CC, wq, AD, AD, nullptr, nullptr, 0, qbuf, AD, BNR);
    // 5. SR convs + LN + GELU
    sr_kernel<8, 7><<<dim3(M1, BB), dim3(192), 0, stream>>>(ybuf + CD, sr1_w, sr1_b, an1_g, an1_b, x1g);
    sr_kernel<4, 14><<<dim3(M2, BB), dim3(192), 0, stream>>>(ybuf + CD, sr2_w, sr2_b, an2_g, an2_b, x2g);
    // 6. kv GEMMs (bf16 out)
    gemm_mfma<4><<<dim3(2, (BB * M1 + 255) / 256), b512, 0, stream>>>(
        x1g, AD, wkv1, AD, AD, nullptr, nullptr, 0, kv1b, AD, BB * M1);
    gemm_mfma<4><<<dim3(2, (BB * M2 + 255) / 256), b512, 0, stream>>>(
        x2g, AD, wkv2, AD, AD, nullptr, nullptr, 0, kv2b, AD, BB * M2);
    // 7. attention, BOTH groups in one dispatch -> cat cols [0,192)
    attn_both<<<dim3((NN + 255) / 256, NH, BB), b256, 0, stream>>>(qbuf, kv1b, kv2b, cat);
    // 8. proj + bias + residual + fused LN2 (bf16 spine; writes xbuf AND ybuf)
    projln_kernel<<<dim3(BNR / 128), b512, 0, stream>>>(
        cat, wpr, proj_b, n2_g, n2_b, xbuf, ybuf);
    // 10. MLP (CB2=16 -> single pass); fc1/fc2 use the 16-wave 8-phase GEMM (R25 config)
    ushort* z1 = (ushort*)(ws + zmark);
    ushort* z2 = z1 + (size_t)CB2 * NN * HID;
    for (int c0 = 0; c0 < BB; c0 += CB2) {
        size_t tokoff = (size_t)c0 * NN;
        int Rr = CB2 * NN;
        gemm_8ph<9><<<dim3(HID / 256, Rr / 256), b1024, 0, stream>>>(
            ybuf + tokoff * CC, CC, wf1, CC, HID, fc1_b, nullptr, 0, z1, HID, Rr);
        dwconv_kernel<<<dim3(HH * 7, CB2), b256, 0, stream>>>(z1, dwwt, dw_b, z2);
        gemm_8ph<3, 1><<<dim3(CC / 256, Rr / 256), b1024, 0, stream>>>(
            z2, HID, wf2, HID, CC, fc2_b, xbuf + tokoff * CC, CC, out + tokoff * CC, CC, Rr);
    }
}

// Round 28
// 339.451 us; speedup vs baseline: 1.1024x; 1.0201x over previous
//
#include <hip/hip_runtime.h>
#include <math.h>

// Problem constants (B=16, H=W=56, C=256)
#define BB   16
#define HH   56
#define WW   56
#define NN   (HH*WW)        // 3136
#define CC   256
#define CD   64
#define AD   192
#define NH   8
#define HG   4
#define HD   24
#define HID  1024
#define M1   49
#define M2   196
#define BNR  (BB*NN)        // 50176

typedef __attribute__((ext_vector_type(8))) short s8v;       // 8 bf16/f16 bit-patterns
typedef __attribute__((ext_vector_type(4))) short s4v;
typedef __attribute__((ext_vector_type(4))) float f4v;
typedef __attribute__((ext_vector_type(8))) _Float16 h8v;    // 8 f16
typedef __attribute__((ext_vector_type(2))) _Float16 h2v;    // 2 f16 (packed math)

// tanh-form GELU; max dev from erf-GELU ~3e-4
__device__ __forceinline__ float gelu_f(float x) {
    float u = x * (1.0f + 0.044715f * x * x);
    float t = __expf(-1.5957691216f * u);
    return x * __builtin_amdgcn_rcpf(1.0f + t);
}
__device__ __forceinline__ ushort f2bf(float f) {
    union { float f; uint32_t u; } c; c.f = f;
    uint32_t u = c.u;
    return (ushort)((u + 0x7fffu + ((u >> 16) & 1u)) >> 16);
}
__device__ __forceinline__ float bf2f(ushort u) {
    union { uint32_t u; float f; } c; c.u = ((uint32_t)u) << 16;
    return c.f;
}
__device__ __forceinline__ ushort f2h(float f) {
    union { _Float16 h; ushort u; } c; c.h = (_Float16)f;
    return c.u;
}
// async global->LDS, 16B per lane; dest = wave-uniform base + lane*16
__device__ __forceinline__ void load_lds16(const void* gsrc, void* ldst) {
    __builtin_amdgcn_global_load_lds(
        (const __attribute__((address_space(1))) void*)gsrc,
        (__attribute__((address_space(3))) void*)ldst, 16, 0, 0);
}
// bijective XCD-chunked block swizzle (m204)
__device__ __forceinline__ int xcd_swz(int bid, int nwg) {
    int q = nwg >> 3, r = nwg & 7;
    int x = bid & 7, i = bid >> 3;
    return (x < r ? x * (q + 1) : r * (q + 1) + (x - r) * q) + i;
}

// ---------------- fused weight prep: all converts/transposes in ONE launch ----------------
__global__ __launch_bounds__(256) void wprep_kernel(
        const float* __restrict__ qw, const float* __restrict__ k1,
        const float* __restrict__ k2, const float* __restrict__ pw,
        const float* __restrict__ f1, const float* __restrict__ f2,
        const float* __restrict__ cw, const float* __restrict__ lw,
        const float* __restrict__ dw,
        ushort* __restrict__ wq, ushort* __restrict__ wkv1,
        ushort* __restrict__ wkv2, ushort* __restrict__ wpr,
        ushort* __restrict__ wf1, ushort* __restrict__ wf2,
        ushort* __restrict__ wcp, float* __restrict__ lpwt,
        ushort* __restrict__ dwwth) {
    int i = blockIdx.x * 256 + threadIdx.x;
    if (i < 36864) { wq[i] = f2bf(qw[i]); return; } i -= 36864;
    if (i < 36864) { wkv1[i] = f2bf(k1[i]); return; } i -= 36864;
    if (i < 36864) { wkv2[i] = f2bf(k2[i]); return; } i -= 36864;
    if (i < 65536) { wpr[i] = f2bf(pw[i]); return; } i -= 65536;
    if (i < 262144) { wf1[i] = f2bf(f1[i]); return; } i -= 262144;
    if (i < 262144) { wf2[i] = f2h(f2[i]); return; } i -= 262144;
    if (i < 36864) {
        int co = i / 576, k = i - co * 576;
        int tap = k >> 6, ci = k & 63;
        wcp[i] = f2bf(cw[co * 576 + ci * 9 + tap]);
        return;
    } i -= 36864;
    if (i < 2304) { int c = i / 9, t = i - c * 9; lpwt[t * CC + c] = lw[i]; return; } i -= 2304;
    if (i < 9216) { int c = i / 9, t = i - c * 9; dwwth[t * HID + c] = f2h(dw[i]); }
}

// ---------------- LPU x-walk: dw3x3 + bias + residual + fused LN1; 4 px/wave ----------------
__global__ __launch_bounds__(256) void lpu_kernel(const float* __restrict__ x,
        const float* __restrict__ wt, const float* __restrict__ bias,
        const float* __restrict__ n1g, const float* __restrict__ n1b,
        ushort* __restrict__ xbuf, ushort* __restrict__ ybuf) {
    int tid = threadIdx.x;
    int lane = tid & 63, wv = tid >> 6;
    int c = lane * 4;
    int grp = xcd_swz(blockIdx.x, NN / 16) * 4 + wv;
    int n0 = grp * 4;
    int h = n0 / WW, x0 = n0 - h * WW;
    int b = blockIdx.y;
    const float* xb = x + (size_t)b * NN * CC + c;
    float4 wreg[9];
#pragma unroll
    for (int t = 0; t < 9; ++t) wreg[t] = *(const float4*)(wt + t * CC + c);
    float4 bz = *(const float4*)(bias + c);
    float4 acc[4] = {bz, bz, bz, bz};
#pragma unroll
    for (int cx = 0; cx < 6; ++cx) {
        int wx = x0 + cx - 1;
        if ((unsigned)wx >= (unsigned)WW) continue;
#pragma unroll
        for (int ky = 0; ky < 3; ++ky) {
            int hy = h + ky - 1;
            if ((unsigned)hy >= (unsigned)HH) continue;
            float4 xv = *(const float4*)(xb + (size_t)(hy * WW + wx) * CC);
#pragma unroll
            for (int xo = 0; xo < 4; ++xo) {
                int kx = cx - xo;
                if (kx < 0 || kx > 2) continue;
                float4 wv4 = wreg[ky * 3 + kx];
                acc[xo].x = fmaf(xv.x, wv4.x, acc[xo].x);
                acc[xo].y = fmaf(xv.y, wv4.y, acc[xo].y);
                acc[xo].z = fmaf(xv.z, wv4.z, acc[xo].z);
                acc[xo].w = fmaf(xv.w, wv4.w, acc[xo].w);
            }
        }
    }
    float4 gv = *(const float4*)(n1g + c);
    float4 bv = *(const float4*)(n1b + c);
#pragma unroll
    for (int xo = 0; xo < 4; ++xo) {
        size_t o = ((size_t)b * NN + n0 + xo) * CC + c;
        float4 rv = *(const float4*)(x + o);
        float4 a = acc[xo];
        a.x += rv.x; a.y += rv.y; a.z += rv.z; a.w += rv.w;
        s4v xv4;
        xv4.x = (short)f2bf(a.x);
        xv4.y = (short)f2bf(a.y);
        xv4.z = (short)f2bf(a.z);
        xv4.w = (short)f2bf(a.w);
        *(s4v*)(xbuf + o) = xv4;
        float s = a.x + a.y + a.z + a.w;
        float sq = a.x * a.x + a.y * a.y + a.z * a.z + a.w * a.w;
#pragma unroll
        for (int off = 32; off >= 1; off >>= 1) {
            s += __shfl_xor(s, off, 64);
            sq += __shfl_xor(sq, off, 64);
        }
        float mean = s * (1.0f / 256.0f);
        float var = sq * (1.0f / 256.0f) - mean * mean;
        float rstd = rsqrtf(var + 1e-5f);
        s4v ov;
        ov.x = (short)f2bf((a.x - mean) * rstd * gv.x + bv.x);
        ov.y = (short)f2bf((a.y - mean) * rstd * gv.y + bv.y);
        ov.z = (short)f2bf((a.z - mean) * rstd * gv.z + bv.z);
        ov.w = (short)f2bf((a.w - mean) * rstd * gv.w + bv.w);
        *(s4v*)(ybuf + o) = ov;
    }
}

// ---------------- cp branch: implicit-GEMM conv + fused LN(64)+GELU epilogue ----------------
__global__ __launch_bounds__(256) void cpgemm_kernel(
        const ushort* __restrict__ y, const ushort* __restrict__ wt,
        const float* __restrict__ cb, const float* __restrict__ cng,
        const float* __restrict__ cnb, ushort* __restrict__ cat) {
    __shared__ __align__(16) ushort As[128 * 32];
    __shared__ __align__(16) ushort Ws[64 * 32];
    int tid = threadIdx.x;
    int wid = tid >> 6, lane = tid & 63;
    int rt = xcd_swz(blockIdx.x, BNR / 128) * 128;
    int r0 = tid >> 2, c0 = tid & 3;
    int r1 = r0 + 64;
    int tok0 = rt + r0, tok1 = rt + r1;
    int b0 = tok0 / NN, n0 = tok0 - b0 * NN, h0 = n0 / WW, w0 = n0 - h0 * WW;
    int b1 = tok1 / NN, n1 = tok1 - b1 * NN, h1 = n1 / WW, w1 = n1 - h1 * WW;
    const ushort* Wp = wt + (size_t)r0 * 576 + c0 * 8;
    int aw0 = (c0 ^ (r0 & 3)) << 3;
    f4v acc[2][4];
#pragma unroll
    for (int m = 0; m < 2; ++m)
#pragma unroll
        for (int n = 0; n < 4; ++n) acc[m][n] = (f4v)0.f;
    int lr = lane & 15, g4 = lane >> 4;
    int swz = (g4 ^ (lr & 3)) << 3;
    for (int kt = 0; kt < 576; kt += 32) {
        int tap = kt >> 6, ci0 = kt & 63;
        int t3 = tap / 3, dy = t3 - 1, dx = (tap - t3 * 3) - 1;
        s8v a0 = (s8v)0, a1 = (s8v)0;
        int hy0 = h0 + dy, wx0 = w0 + dx;
        if ((unsigned)hy0 < (unsigned)HH && (unsigned)wx0 < (unsigned)WW)
            a0 = *(const s8v*)(y + ((size_t)b0 * NN + hy0 * WW + wx0) * CC + ci0 + c0 * 8);
        int hy1 = h1 + dy, wx1 = w1 + dx;
        if ((unsigned)hy1 < (unsigned)HH && (unsigned)wx1 < (unsigned)WW)
            a1 = *(const s8v*)(y + ((size_t)b1 * NN + hy1 * WW + wx1) * CC + ci0 + c0 * 8);
        s8v wv = *(const s8v*)(Wp + kt);
        __syncthreads();
        *(s8v*)&As[r0 * 32 + aw0] = a0;
        *(s8v*)&As[r1 * 32 + aw0] = a1;
        *(s8v*)&Ws[r0 * 32 + aw0] = wv;
        __syncthreads();
        s8v af[2], bf[4];
#pragma unroll
        for (int m = 0; m < 2; ++m)
            af[m] = *(const s8v*)&As[(wid * 32 + m * 16 + lr) * 32 + swz];
#pragma unroll
        for (int n = 0; n < 4; ++n)
            bf[n] = *(const s8v*)&Ws[(n * 16 + lr) * 32 + swz];
#pragma unroll
        for (int m = 0; m < 2; ++m)
#pragma unroll
            for (int n = 0; n < 4; ++n)
                acc[m][n] = __builtin_amdgcn_mfma_f32_16x16x32_bf16(af[m], bf[n], acc[m][n], 0, 0, 0);
    }
    float gv[4], bv[4], cbv[4];
#pragma unroll
    for (int n = 0; n < 4; ++n) {
        int gc = n * 16 + lr;
        cbv[n] = cb[gc];
        gv[n] = cng[gc];
        bv[n] = cnb[gc];
    }
#pragma unroll
    for (int m = 0; m < 2; ++m)
#pragma unroll
        for (int r = 0; r < 4; ++r) {
            float s = 0.f, sq = 0.f;
#pragma unroll
            for (int n = 0; n < 4; ++n) {
                float v = acc[m][n][r] + cbv[n];
                acc[m][n][r] = v;
                s += v; sq += v * v;
            }
#pragma unroll
            for (int off = 1; off < 16; off <<= 1) {
                s += __shfl_xor(s, off, 64);
                sq += __shfl_xor(sq, off, 64);
            }
            float mean = s * (1.0f / 64.0f);
            float var = sq * (1.0f / 64.0f) - mean * mean;
            float rstd = rsqrtf(var + 1e-5f);
            int row = rt + wid * 32 + m * 16 + g4 * 4 + r;
            ushort* op = cat + (size_t)row * CC + 192;
#pragma unroll
            for (int n = 0; n < 4; ++n) {
                float v = (acc[m][n][r] - mean) * rstd * gv[n] + bv[n];
                op[n * 16 + lr] = f2bf(gelu_f(v));
            }
        }
}

// ---------------- SR conv body (depthwise KSxKS stride KS) + LN(192) + GELU, bf16 io ----------------
template <int KS, int OW>
__device__ __forceinline__ void sr_body(const ushort* __restrict__ yap,
        const float* __restrict__ w, const float* __restrict__ bias,
        const float* __restrict__ g, const float* __restrict__ bt,
        ushort* __restrict__ out, int m, int b) {
    int ch = threadIdx.x;
    int oh = m / OW, ow = m - oh * OW;
    const ushort* yb = yap + (size_t)b * NN * CC;
    float acc = bias[ch];
#pragma unroll
    for (int ky = 0; ky < KS; ++ky)
#pragma unroll
        for (int kx = 0; kx < KS; ++kx)
            acc = fmaf(bf2f(yb[(size_t)((oh * KS + ky) * WW + ow * KS + kx) * CC + ch]),
                       w[ch * KS * KS + ky * KS + kx], acc);
    __shared__ float red[2][3];
    float s = acc, sq = acc * acc;
#pragma unroll
    for (int off = 32; off >= 1; off >>= 1) {
        s += __shfl_xor(s, off, 64);
        sq += __shfl_xor(sq, off, 64);
    }
    int wv = threadIdx.x >> 6, lane = threadIdx.x & 63;
    if (lane == 0) { red[0][wv] = s; red[1][wv] = sq; }
    __syncthreads();
    s = red[0][0] + red[0][1] + red[0][2];
    sq = red[1][0] + red[1][1] + red[1][2];
    float mean = s * (1.0f / 192.0f);
    float var = sq * (1.0f / 192.0f) - mean * mean;
    float rstd = rsqrtf(var + 1e-5f);
    float v = (acc - mean) * rstd * g[ch] + bt[ch];
    out[((size_t)b * (OW * OW) + m) * AD + ch] = f2bf(gelu_f(v));
}

// merged SR convs: blockIdx.x in [0,M2) -> sr2 (4x4); [M2,M2+M1) -> sr1 (8x8)
__global__ __launch_bounds__(192) void sr_both(const ushort* __restrict__ yap,
        const float* __restrict__ w1, const float* __restrict__ b1,
        const float* __restrict__ g1, const float* __restrict__ t1,
        ushort* __restrict__ o1,
        const float* __restrict__ w2, const float* __restrict__ b2,
        const float* __restrict__ g2, const float* __restrict__ t2,
        ushort* __restrict__ o2) {
    int b = blockIdx.y;
    if (blockIdx.x < M2) sr_body<4, 14>(yap, w2, b2, g2, t2, o2, blockIdx.x, b);
    else                 sr_body<8, 7>(yap, w1, b1, g1, t1, o1, blockIdx.x - M2, b);
}

// ---------------- MFMA GEMM body: 256x128 tile, 512 thr / 8 waves, 2-phase ----------------
// MODE bits: 1=bias(fp32), 2=residual(bf16, stride ldr), 4=output bf16, 8=output f16 (else fp32)
template <int MODE, int F16>
__device__ __forceinline__ void gemm_body(
        const ushort* __restrict__ A, int lda,
        const ushort* __restrict__ W, int K, int O,
        const float* __restrict__ bias,
        const ushort* __restrict__ res, int ldr,
        void* __restrict__ Cout, int ldc, int R,
        int gx, int nwg, int bid) {
    __shared__ __align__(16) ushort As[2 * 256 * 32];   // 32KB
    __shared__ __align__(16) ushort Ws[2 * 128 * 32];   // 16KB
    int tid = threadIdx.x;
    int w8 = tid >> 6, lane = tid & 63;
    int wr = w8 >> 1, wc = w8 & 1;
    int swzb = xcd_swz(bid, nwg);
    int rt = (swzb / gx) * 256, ot = (swzb % gx) * 128;
    int r0 = tid >> 2, cslot = tid & 3;
    int csrc = (cslot ^ (r0 & 3)) * 8;
    const ushort* Ap0 = A + (size_t)min(rt + r0, R - 1) * lda + csrc;
    const ushort* Ap1 = A + (size_t)min(rt + r0 + 128, R - 1) * lda + csrc;
    const ushort* Wp0 = W + (size_t)min(ot + r0, O - 1) * K + csrc;
    char* lA0 = (char*)As + w8 * 1024;
    char* lA1 = (char*)As + 8192 + w8 * 1024;
    char* lW0 = (char*)Ws + w8 * 1024;
    f4v acc[4][4];
#pragma unroll
    for (int m = 0; m < 4; ++m)
#pragma unroll
        for (int n = 0; n < 4; ++n) acc[m][n] = (f4v)0.f;
    int lr = lane & 15;
    int swz = ((lane >> 4) ^ (lr & 3)) << 3;
    load_lds16(Ap0, lA0);
    load_lds16(Ap1, lA1);
    load_lds16(Wp0, lW0);
    __syncthreads();
    int cur = 0;
    for (int kt = 0; kt < K; kt += 32) {
        if (kt + 32 < K) {
            int pa = (cur ^ 1) * 16384, pw = (cur ^ 1) * 8192;
            load_lds16(Ap0 + kt + 32, lA0 + pa);
            load_lds16(Ap1 + kt + 32, lA1 + pa);
            load_lds16(Wp0 + kt + 32, lW0 + pw);
        }
        const ushort* Ab = As + cur * 8192;
        const ushort* Wb = Ws + cur * 4096;
        s8v af[4], bf[4];
#pragma unroll
        for (int m = 0; m < 4; ++m)
            af[m] = *(const s8v*)&Ab[(wr * 64 + m * 16 + lr) * 32 + swz];
#pragma unroll
        for (int n = 0; n < 4; ++n)
            bf[n] = *(const s8v*)&Wb[(wc * 64 + n * 16 + lr) * 32 + swz];
#pragma unroll
        for (int m = 0; m < 4; ++m)
#pragma unroll
            for (int n = 0; n < 4; ++n) {
                if (F16) {
                    h8v ah = *(const h8v*)&af[m];
                    h8v bh = *(const h8v*)&bf[n];
                    acc[m][n] = __builtin_amdgcn_mfma_f32_16x16x32_f16(ah, bh, acc[m][n], 0, 0, 0);
                } else {
                    acc[m][n] = __builtin_amdgcn_mfma_f32_16x16x32_bf16(af[m], bf[n], acc[m][n], 0, 0, 0);
                }
            }
        __syncthreads();
        cur ^= 1;
    }
#pragma unroll
    for (int m = 0; m < 4; ++m)
#pragma unroll
        for (int n = 0; n < 4; ++n) {
            int gr = rt + wr * 64 + m * 16 + (lane >> 4) * 4;
            int gc = ot + wc * 64 + n * 16 + (lane & 15);
            if (gc >= O) continue;
#pragma unroll
            for (int r = 0; r < 4; ++r) {
                int row = gr + r;
                if (row >= R) continue;
                float v = acc[m][n][r];
                if (MODE & 1) v += bias[gc];
                if (MODE & 2) v += bf2f(res[(size_t)row * ldr + gc]);
                if (MODE & 4)      ((ushort*)Cout)[(size_t)row * ldc + gc] = f2bf(v);
                else if (MODE & 8) ((ushort*)Cout)[(size_t)row * ldc + gc] = f2h(v);
                else               ((float*)Cout)[(size_t)row * ldc + gc] = v;
            }
        }
}

template <int MODE, int F16 = 0>
__global__ __launch_bounds__(512) void gemm_mfma(
        const ushort* __restrict__ A, int lda,
        const ushort* __restrict__ W, int K, int O,
        const float* __restrict__ bias,
        const ushort* __restrict__ res, int ldr,
        void* __restrict__ Cout, int ldc, int R) {
    gemm_body<MODE, F16>(A, lda, W, K, O, bias, res, ldr, Cout, ldc, R,
                         gridDim.x, gridDim.x * gridDim.y,
                         blockIdx.y * gridDim.x + blockIdx.x);
}

// merged kv GEMMs: blockIdx.z selects problem; z=0 (kv1) uses only y<4
__global__ __launch_bounds__(512) void kv_both(
        const ushort* __restrict__ x1g, const ushort* __restrict__ wkv1,
        ushort* __restrict__ kv1b,
        const ushort* __restrict__ x2g, const ushort* __restrict__ wkv2,
        ushort* __restrict__ kv2b) {
    int bid = blockIdx.y * 2 + blockIdx.x;
    if (blockIdx.z == 0) {
        if (blockIdx.y >= 4) return;
        gemm_body<4, 0>(x1g, AD, wkv1, AD, AD, nullptr, nullptr, 0,
                        kv1b, AD, BB * M1, 2, 8, bid);
    } else {
        gemm_body<4, 0>(x2g, AD, wkv2, AD, AD, nullptr, nullptr, 0,
                        kv2b, AD, BB * M2, 2, 26, bid);
    }
}

// ---------------- 16-wave 8-phase GEMM: 256x256 tile, BK=64, counted vmcnt, depth-3 ----------------
// (R25 best-measured: 1024 thr / 16 waves (4x4), wave 64x64 out, 128KB LDS, vmcnt(4) steady)
template <int MODE, int F16 = 0>
__global__ __launch_bounds__(1024) void gemm_8ph(
        const ushort* __restrict__ A, int lda,
        const ushort* __restrict__ W, int K, int O,
        const float* __restrict__ bias,
        const ushort* __restrict__ res, int ldr,
        void* __restrict__ Cout, int ldc, int R) {
    __shared__ __align__(16) ushort Al[2 * 256 * 64];   // 64KB
    __shared__ __align__(16) ushort Wl[2 * 256 * 64];   // 64KB
    int tid = threadIdx.x;
    int w16 = tid >> 6, lane = tid & 63;
    int wr = w16 >> 2, wc = w16 & 3;          // 4 x 4 wave grid
    int nwg = gridDim.x * gridDim.y;
    int swzb = xcd_swz(blockIdx.y * gridDim.x + blockIdx.x, nwg);
    int rt = (swzb / gridDim.x) * 256, ot = (swzb % gridDim.x) * 256;
    int lr = lane & 15, g4 = lane >> 4;
    int swz = (g4 ^ (lr & 3)) << 3;
    int ar0 = tid >> 2, sp0 = tid & 3;        // 1024 units cover all 256 rows x 4 slots
    int cs0 = ((sp0 ^ (ar0 & 3)) << 3);       // inverse-swizzled source K-slot
    const ushort* Ap0 = A + (size_t)(rt + ar0) * lda + cs0;
    const ushort* Wp0 = W + (size_t)(ot + ar0) * K + cs0;
    int d0 = w16 * 1024;                       // LDS dest byte offset (lane*16 implicit)
    f4v acc[4][4];
#pragma unroll
    for (int m = 0; m < 4; ++m)
#pragma unroll
        for (int n = 0; n < 4; ++n)
            acc[m][n] = (f4v)((MODE & 1) ? bias[ot + wc * 64 + n * 16 + lr] : 0.0f);
    auto STAGE = [&](int s) {
        int t = s >> 1, hf = s & 1;
        int boff = (t & 1) * 32768 + hf * 16384;   // byte offset in each LDS array
        int kc = t * 64 + hf * 32;
        load_lds16(Ap0 + kc, (char*)Al + boff + d0);
        load_lds16(Wp0 + kc, (char*)Wl + boff + d0);
    };
    int nS = K >> 5;                           // half-stages (32-K each)
    STAGE(0); STAGE(1); STAGE(2);
    for (int s = 0; s < nS; ++s) {
        if (s < nS - 2)       asm volatile("s_waitcnt vmcnt(4)" ::: "memory");
        else if (s == nS - 2) asm volatile("s_waitcnt vmcnt(2)" ::: "memory");
        else                  asm volatile("s_waitcnt vmcnt(0)" ::: "memory");
        __builtin_amdgcn_s_barrier();
        __builtin_amdgcn_sched_barrier(0);
        if (s + 3 < nS) STAGE(s + 3);
        int uoff = ((s >> 1) & 1) * 16384 + (s & 1) * 8192;   // ushort index offset
        const ushort* Ab = Al + uoff;
        const ushort* Wb = Wl + uoff;
        s8v af[4], bf[4];
#pragma unroll
        for (int m = 0; m < 4; ++m)
            af[m] = *(const s8v*)&Ab[(wr * 64 + m * 16 + lr) * 32 + swz];
#pragma unroll
        for (int n = 0; n < 4; ++n)
            bf[n] = *(const s8v*)&Wb[(wc * 64 + n * 16 + lr) * 32 + swz];
        __builtin_amdgcn_s_setprio(1);
#pragma unroll
        for (int m = 0; m < 4; ++m)
#pragma unroll
            for (int n = 0; n < 4; ++n) {
                if (F16) {
                    h8v ah = *(const h8v*)&af[m];
                    h8v bh = *(const h8v*)&bf[n];
                    acc[m][n] = __builtin_amdgcn_mfma_f32_16x16x32_f16(ah, bh, acc[m][n], 0, 0, 0);
                } else {
                    acc[m][n] = __builtin_amdgcn_mfma_f32_16x16x32_bf16(af[m], bf[n], acc[m][n], 0, 0, 0);
                }
            }
        __builtin_amdgcn_s_setprio(0);
    }
#pragma unroll
    for (int m = 0; m < 4; ++m) {
        int gr = rt + wr * 64 + m * 16 + g4 * 4;
#pragma unroll
        for (int n = 0; n < 4; ++n) {
            int gc = ot + wc * 64 + n * 16 + lr;
#pragma unroll
            for (int r = 0; r < 4; ++r) {
                int row = gr + r;
                float v = acc[m][n][r];
                if (MODE & 2) v += bf2f(res[(size_t)row * ldr + gc]);
                if (MODE & 4)      ((ushort*)Cout)[(size_t)row * ldc + gc] = f2bf(v);
                else if (MODE & 8) ((ushort*)Cout)[(size_t)row * ldc + gc] = f2h(v);
                else               ((float*)Cout)[(size_t)row * ldc + gc] = v;
            }
        }
    }
}

// ---------------- proj (O=256) + bias + residual + fused LN2 ----------------
__global__ __launch_bounds__(512) void projln_kernel(
        const ushort* __restrict__ A, const ushort* __restrict__ W,
        const float* __restrict__ bias,
        const float* __restrict__ n2g, const float* __restrict__ n2b,
        ushort* __restrict__ xbuf, ushort* __restrict__ ybuf) {
    __shared__ __align__(16) ushort As[128 * 32];   // 8KB
    __shared__ __align__(16) ushort Ws[256 * 32];   // 16KB
    int tid = threadIdx.x;
    int w8 = tid >> 6, lane = tid & 63;
    int rt = xcd_swz(blockIdx.x, BNR / 128) * 128;
    int r0 = tid >> 2, cslot = tid & 3;
    int csrc = (cslot ^ (r0 & 3)) * 8;
    const ushort* Ap0 = A + (size_t)(rt + r0) * CC + csrc;
    const ushort* Wp0 = W + (size_t)r0 * CC + csrc;
    const ushort* Wp1 = W + (size_t)(r0 + 128) * CC + csrc;
    char* lA0 = (char*)As + w8 * 1024;
    char* lW0 = (char*)Ws + w8 * 1024;
    char* lW1 = (char*)Ws + 8192 + w8 * 1024;
    int lr = lane & 15, g4 = lane >> 4;
    int swz = (g4 ^ (lr & 3)) << 3;
    f4v acc[16];
#pragma unroll
    for (int n = 0; n < 16; ++n) acc[n] = (f4v)(bias[n * 16 + lr]);
    for (int kt = 0; kt < CC; kt += 32) {
        __syncthreads();
        load_lds16(Ap0 + kt, lA0);
        load_lds16(Wp0 + kt, lW0);
        load_lds16(Wp1 + kt, lW1);
        __syncthreads();
        s8v af = *(const s8v*)&As[(w8 * 16 + lr) * 32 + swz];
#pragma unroll
        for (int n = 0; n < 16; ++n) {
            s8v bf = *(const s8v*)&Ws[(n * 16 + lr) * 32 + swz];
            acc[n] = __builtin_amdgcn_mfma_f32_16x16x32_bf16(af, bf, acc[n], 0, 0, 0);
        }
    }
#pragma unroll
    for (int r = 0; r < 4; ++r) {
        int row = rt + w8 * 16 + g4 * 4 + r;
        ushort* xr = xbuf + (size_t)row * CC;
        ushort* yr = ybuf + (size_t)row * CC;
        float s = 0.f, sq = 0.f;
#pragma unroll
        for (int n = 0; n < 16; ++n) {
            float v = acc[n][r] + bf2f(xr[n * 16 + lr]);
            acc[n][r] = v;
            s += v; sq += v * v;
        }
#pragma unroll
        for (int off = 1; off < 16; off <<= 1) {
            s += __shfl_xor(s, off, 64);
            sq += __shfl_xor(sq, off, 64);
        }
        float mean = s * (1.0f / 256.0f);
        float var = sq * (1.0f / 256.0f) - mean * mean;
        float rstd = rsqrtf(var + 1e-5f);
#pragma unroll
        for (int n = 0; n < 16; ++n) {
            int col = n * 16 + lr;
            float v = acc[n][r];
            xr[col] = f2bf(v);
            yr[col] = f2bf((v - mean) * rstd * n2g[col] + n2b[col]);
        }
    }
}

// ---------------- MFMA attention body (shared by both K/V groups) ----------------
template <int M, int MP>
__device__ __forceinline__ void attn_body(const ushort* __restrict__ q,
        const ushort* __restrict__ kvb, ushort* __restrict__ cat,
        ushort* Kl, ushort* VT, int g, int h, int b) {
    constexpr int NT = MP / 16;
    constexpr int NCH = MP / 32;
    int tid = threadIdx.x;
    for (int i = tid; i < MP * 4; i += 256) ((s8v*)Kl)[i] = (s8v)0;
    for (int i = tid; i < MP * 4; i += 256) ((s8v*)VT)[i] = (s8v)0;
    __syncthreads();
    for (int u = tid; u < M * 3; u += 256) {
        int m = u / 3, d0 = u - m * 3;
        s8v kv8 = *(const s8v*)(kvb + ((size_t)b * M + m) * AD + g * HD + d0 * 8);
        *(s8v*)&Kl[m * 32 + ((d0 ^ (m & 3)) << 3)] = kv8;
    }
    for (int u = tid; u < M * 3; u += 256) {
        int m = u / 3, d0 = u - m * 3;
        s8v vv = *(const s8v*)(kvb + ((size_t)b * M + m) * AD + 96 + g * HD + d0 * 8);
        int c = m >> 5, mm = m & 31;
        int gg = (mm >> 2) & 3;
        int t = (mm & 3) + ((mm & 16) >> 2);
#pragma unroll
        for (int j = 0; j < 8; ++j) {
            int d = d0 * 8 + j;
            VT[d * MP + ((c * 4 + (gg ^ (d & 3))) << 3) + t] = (ushort)vv[j];
        }
    }
    __syncthreads();
    int w = tid >> 6, lane = tid & 63;
    int ln = lane & 15, g4 = lane >> 4;
    int swz = (g4 ^ (ln & 3)) << 3;
    const float scale = 0.20412414523193154f;  // 24^-0.5
    for (int nt = 0; nt < 4; ++nt) {
        int nbase = blockIdx.x * 256 + nt * 64;
        if (nbase >= NN) break;
        int n0 = nbase + w * 16 + ln;
        s8v qf = (s8v)0;
        if (g4 < 3) qf = *(const s8v*)(q + ((size_t)b * NN + n0) * AD + h * HD + g4 * 8);
        f4v sa[NT];
#pragma unroll
        for (int t = 0; t < NT; ++t) sa[t] = (f4v)0.f;
#pragma unroll
        for (int t = 0; t < NT; ++t) {
            s8v kf = *(const s8v*)&Kl[(t * 16 + ln) * 32 + swz];
            sa[t] = __builtin_amdgcn_mfma_f32_16x16x32_bf16(kf, qf, sa[t], 0, 0, 0);
        }
        float mx = -3.0e38f;
#pragma unroll
        for (int t = 0; t < NT; ++t)
#pragma unroll
            for (int r = 0; r < 4; ++r) {
                int m = t * 16 + g4 * 4 + r;
                float v = (m < M) ? sa[t][r] * scale : -3.0e38f;
                sa[t][r] = v;
                mx = fmaxf(mx, v);
            }
        mx = fmaxf(mx, __shfl_xor(mx, 16, 64));
        mx = fmaxf(mx, __shfl_xor(mx, 32, 64));
        float sum = 0.f;
#pragma unroll
        for (int t = 0; t < NT; ++t)
#pragma unroll
            for (int r = 0; r < 4; ++r) {
                float p = __expf(sa[t][r] - mx);
                sa[t][r] = p;
                sum += p;
            }
        sum += __shfl_xor(sum, 16, 64);
        sum += __shfl_xor(sum, 32, 64);
        float inv = 1.0f / sum;
        f4v oa[2] = {(f4v)0.f, (f4v)0.f};
#pragma unroll
        for (int c = 0; c < NCH; ++c) {
            s8v pb;
#pragma unroll
            for (int t = 0; t < 4; ++t) {
                pb[t]     = (short)f2bf(sa[c * 2][t]);
                pb[4 + t] = (short)f2bf(sa[c * 2 + 1][t]);
            }
#pragma unroll
            for (int dt = 0; dt < 2; ++dt) {
                s8v vf = *(const s8v*)&VT[(dt * 16 + ln) * MP + c * 32 + swz];
                oa[dt] = __builtin_amdgcn_mfma_f32_16x16x32_bf16(vf, pb, oa[dt], 0, 0, 0);
            }
        }
        ushort* op = cat + ((size_t)b * NN + n0) * CC + h * HD;
        s4v o0;
#pragma unroll
        for (int r = 0; r < 4; ++r) o0[r] = (short)f2bf(oa[0][r] * inv);
        *(s4v*)(op + g4 * 4) = o0;
        if (g4 < 2) {
            s4v o1;
#pragma unroll
            for (int r = 0; r < 4; ++r) o1[r] = (short)f2bf(oa[1][r] * inv);
            *(s4v*)(op + 16 + g4 * 4) = o1;
        }
    }
}

// merged attention: blockIdx.y in [0,8) covers both K/V groups in ONE dispatch
__global__ __launch_bounds__(256) void attn_both(const ushort* __restrict__ q,
        const ushort* __restrict__ kv1b, const ushort* __restrict__ kv2b,
        ushort* __restrict__ cat) {
    __shared__ __align__(16) ushort Kl[224 * 32];
    __shared__ __align__(16) ushort VT[32 * 224];
    int hy = blockIdx.y, b = blockIdx.z;
    if (hy < HG) attn_body<M1, 64>(q, kv1b, cat, Kl, VT, hy, hy, b);
    else         attn_body<M2, 224>(q, kv2b, cat, Kl, VT, hy - HG, hy, b);
}

// ---------------- depthwise 3x3 hid=1024: x-walk, f16 packed math ----------------
__global__ __launch_bounds__(256) void dwconv_kernel(const ushort* __restrict__ z1,
        const ushort* __restrict__ wt, const float* __restrict__ bias,
        ushort* __restrict__ z2) {
    int bid = xcd_swz(blockIdx.x, HH * 7);
    int h = bid / 7, bx = bid - h * 7;
    int b = blockIdx.y;
    int c = (threadIdx.x & 127) * 8;
    int x0 = bx * 8 + (threadIdx.x >> 7) * 4;
    const ushort* zrow = z1 + ((size_t)b * NN + h * WW) * HID + c;
    h2v wreg[9][4];
#pragma unroll
    for (int t = 0; t < 9; ++t) {
        s8v w8 = *(const s8v*)(wt + t * HID + c);
        const h2v* wp = (const h2v*)&w8;
#pragma unroll
        for (int p = 0; p < 4; ++p) wreg[t][p] = wp[p];
    }
    h2v acc[4][4];
    {
        float4 b0 = *(const float4*)(bias + c);
        float4 b1 = *(const float4*)(bias + c + 4);
        h2v bz[4];
        bz[0][0] = (_Float16)b0.x; bz[0][1] = (_Float16)b0.y;
        bz[1][0] = (_Float16)b0.z; bz[1][1] = (_Float16)b0.w;
        bz[2][0] = (_Float16)b1.x; bz[2][1] = (_Float16)b1.y;
        bz[3][0] = (_Float16)b1.z; bz[3][1] = (_Float16)b1.w;
#pragma unroll
        for (int xo = 0; xo < 4; ++xo)
#pragma unroll
            for (int p = 0; p < 4; ++p) acc[xo][p] = bz[p];
    }
#pragma unroll
    for (int cx = 0; cx < 6; ++cx) {
        int wx = x0 + cx - 1;
        if ((unsigned)wx >= (unsigned)WW) continue;
#pragma unroll
        for (int ky = 0; ky < 3; ++ky) {
            int hy = h + ky - 1;
            if ((unsigned)hy >= (unsigned)HH) continue;
            s8v v = *(const s8v*)(zrow + ((size_t)(ky - 1) * WW + wx) * HID);
            const h2v* v2 = (const h2v*)&v;
#pragma unroll
            for (int xo = 0; xo < 4; ++xo) {
                int kx = cx - xo;
                if (kx < 0 || kx > 2) continue;
#pragma unroll
                for (int p = 0; p < 4; ++p)
                    acc[xo][p] = v2[p] * wreg[ky * 3 + kx][p] + acc[xo][p];
            }
        }
    }
    ushort* zo = z2 + ((size_t)b * NN + h * WW + x0) * HID + c;
#pragma unroll
    for (int xo = 0; xo < 4; ++xo) {
        s8v o;
#pragma unroll
        for (int p = 0; p < 4; ++p) {
            o[p * 2]     = (short)f2h(gelu_f((float)acc[xo][p][0]));
            o[p * 2 + 1] = (short)f2h(gelu_f((float)acc[xo][p][1]));
        }
        *(s8v*)(zo + (size_t)xo * HID) = o;
    }
}

extern "C" void kernel_launch(void* const* d_in, const int* in_sizes, int n_in,
                              void* d_out, int out_size, void* d_ws, size_t ws_size,
                              hipStream_t stream) {
    const float* x      = (const float*)d_in[0];
    const float* lpu_w  = (const float*)d_in[3];
    const float* lpu_b  = (const float*)d_in[4];
    const float* n1_g   = (const float*)d_in[5];
    const float* n1_b   = (const float*)d_in[6];
    const float* c2_w   = (const float*)d_in[7];
    const float* c2_b   = (const float*)d_in[8];
    const float* cn_g   = (const float*)d_in[9];
    const float* cn_b   = (const float*)d_in[10];
    const float* q_w    = (const float*)d_in[11];
    const float* sr1_w  = (const float*)d_in[12];
    const float* sr1_b  = (const float*)d_in[13];
    const float* an1_g  = (const float*)d_in[14];
    const float* an1_b  = (const float*)d_in[15];
    const float* sr2_w  = (const float*)d_in[16];
    const float* sr2_b  = (const float*)d_in[17];
    const float* an2_g  = (const float*)d_in[18];
    const float* an2_b  = (const float*)d_in[19];
    const float* kv1_w  = (const float*)d_in[20];
    const float* kv2_w  = (const float*)d_in[21];
    const float* proj_w = (const float*)d_in[22];
    const float* proj_b = (const float*)d_in[23];
    const float* n2_g   = (const float*)d_in[24];
    const float* n2_b   = (const float*)d_in[25];
    const float* fc1_w  = (const float*)d_in[26];
    const float* fc1_b  = (const float*)d_in[27];
    const float* dw_w   = (const float*)d_in[28];
    const float* dw_b   = (const float*)d_in[29];
    const float* fc2_w  = (const float*)d_in[30];
    const float* fc2_b  = (const float*)d_in[31];
    float* out = (float*)d_out;

    char* ws = (char*)d_ws;
    size_t off = 0;
    auto allocB = [&](size_t bytes) {
        char* p = ws + off;
        off += ((bytes + 255) & ~(size_t)255);
        return p;
    };
    ushort* xbuf = (ushort*)allocB((size_t)BNR * CC * 2);  // bf16 residual spine
    ushort* ybuf = (ushort*)allocB((size_t)BNR * CC * 2);  // LN out (bf16)
    ushort* wq   = (ushort*)allocB((size_t)AD * AD * 2);
    ushort* wkv1 = (ushort*)allocB((size_t)AD * AD * 2);
    ushort* wkv2 = (ushort*)allocB((size_t)AD * AD * 2);
    ushort* wpr  = (ushort*)allocB((size_t)CC * CC * 2);
    ushort* wf1  = (ushort*)allocB((size_t)HID * CC * 2);
    ushort* wf2  = (ushort*)allocB((size_t)CC * HID * 2);  // f16
    ushort* wcp  = (ushort*)allocB((size_t)64 * 576 * 2);
    float*  lpwt = (float*)allocB((size_t)9 * CC * 4);
    ushort* dwwt = (ushort*)allocB((size_t)9 * HID * 2);   // f16
    size_t zmark = off;                                    // overlay region start
    ushort* cat  = (ushort*)allocB((size_t)BNR * CC * 2);  // [o1|o2|cp] bf16
    ushort* qbuf = (ushort*)allocB((size_t)BNR * AD * 2);
    ushort* x1g  = (ushort*)allocB((size_t)BB * M1 * AD * 2);
    ushort* x2g  = (ushort*)allocB((size_t)BB * M2 * AD * 2);
    ushort* kv1b = (ushort*)allocB((size_t)BB * M1 * AD * 2);  // bf16 kv
    ushort* kv2b = (ushort*)allocB((size_t)BB * M2 * AD * 2);

    int CB2 = 1;
    for (int cb = 16; cb >= 1; cb >>= 1) {
        if (zmark + 2 * (size_t)cb * NN * HID * 2 <= ws_size) { CB2 = cb; break; }
    }

    dim3 b256(256), b512(512), b1024(1024);
    // 0. fused weight prep (one launch)
    wprep_kernel<<<dim3(2925), b256, 0, stream>>>(
        q_w, kv1_w, kv2_w, proj_w, fc1_w, fc2_w, c2_w, lpu_w, dw_w,
        wq, wkv1, wkv2, wpr, wf1, wf2, wcp, lpwt, dwwt);
    // 1. LPU x-walk + residual + fused LN1 (xbuf bf16 + ybuf bf16)
    lpu_kernel<<<dim3(NN / 16, BB), b256, 0, stream>>>(x, lpwt, lpu_b, n1_g, n1_b, xbuf, ybuf);
    // 3. cp branch: MFMA implicit conv + fused LN64+GELU -> cat cols [192,256)
    cpgemm_kernel<<<dim3(BNR / 128), b256, 0, stream>>>(ybuf, wcp, c2_b, cn_g, cn_b, cat);
    // 4. q = ap @ q_w.T  (bf16 out)
    gemm_mfma<4><<<dim3(2, BNR / 256), b512, 0, stream>>>(
        ybuf + CD, CC, wq, AD, AD, nullptr, nullptr, 0, qbuf, AD, BNR);
    // 5. SR convs (both) + LN + GELU, one dispatch
    sr_both<<<dim3(M1 + M2, BB), dim3(192), 0, stream>>>(ybuf + CD,
        sr1_w, sr1_b, an1_g, an1_b, x1g, sr2_w, sr2_b, an2_g, an2_b, x2g);
    // 6. kv GEMMs (both) in one dispatch (bf16 out)
    kv_both<<<dim3(2, 13, 2), b512, 0, stream>>>(x1g, wkv1, kv1b, x2g, wkv2, kv2b);
    // 7. attention, BOTH groups in one dispatch -> cat cols [0,192)
    attn_both<<<dim3((NN + 255) / 256, NH, BB), b256, 0, stream>>>(qbuf, kv1b, kv2b, cat);
    // 8. proj + bias + residual + fused LN2 (bf16 spine; writes xbuf AND ybuf)
    projln_kernel<<<dim3(BNR / 128), b512, 0, stream>>>(
        cat, wpr, proj_b, n2_g, n2_b, xbuf, ybuf);
    // 10. MLP (CB2=16 -> single pass); fc1/fc2 use the 16-wave 8-phase GEMM (R25 config)
    ushort* z1 = (ushort*)(ws + zmark);
    ushort* z2 = z1 + (size_t)CB2 * NN * HID;
    for (int c0 = 0; c0 < BB; c0 += CB2) {
        size_t tokoff = (size_t)c0 * NN;
        int Rr = CB2 * NN;
        gemm_8ph<9><<<dim3(HID / 256, Rr / 256), b1024, 0, stream>>>(
            ybuf + tokoff * CC, CC, wf1, CC, HID, fc1_b, nullptr, 0, z1, HID, Rr);
        dwconv_kernel<<<dim3(HH * 7, CB2), b256, 0, stream>>>(z1, dwwt, dw_b, z2);
        gemm_8ph<3, 1><<<dim3(CC / 256, Rr / 256), b1024, 0, stream>>>(
            z2, HID, wf2, HID, CC, fc2_b, xbuf + tokoff * CC, CC, out + tokoff * CC, CC, Rr);
    }
}

// Round 29
// 332.225 us; speedup vs baseline: 1.1264x; 1.0218x over previous
//
#include <hip/hip_runtime.h>
#include <math.h>

// Problem constants (B=16, H=W=56, C=256)
#define BB   16
#define HH   56
#define WW   56
#define NN   (HH*WW)        // 3136
#define CC   256
#define CD   64
#define AD   192
#define NH   8
#define HG   4
#define HD   24
#define HID  1024
#define M1   49
#define M2   196
#define BNR  (BB*NN)        // 50176

typedef __attribute__((ext_vector_type(8))) short s8v;       // 8 bf16/f16 bit-patterns
typedef __attribute__((ext_vector_type(4))) short s4v;
typedef __attribute__((ext_vector_type(4))) float f4v;
typedef __attribute__((ext_vector_type(8))) _Float16 h8v;    // 8 f16
typedef __attribute__((ext_vector_type(2))) _Float16 h2v;    // 2 f16 (packed math)

// tanh-form GELU; max dev from erf-GELU ~3e-4
__device__ __forceinline__ float gelu_f(float x) {
    float u = x * (1.0f + 0.044715f * x * x);
    float t = __expf(-1.5957691216f * u);
    return x * __builtin_amdgcn_rcpf(1.0f + t);
}
__device__ __forceinline__ ushort f2bf(float f) {
    union { float f; uint32_t u; } c; c.f = f;
    uint32_t u = c.u;
    return (ushort)((u + 0x7fffu + ((u >> 16) & 1u)) >> 16);
}
__device__ __forceinline__ float bf2f(ushort u) {
    union { uint32_t u; float f; } c; c.u = ((uint32_t)u) << 16;
    return c.f;
}
__device__ __forceinline__ ushort f2h(float f) {
    union { _Float16 h; ushort u; } c; c.h = (_Float16)f;
    return c.u;
}
// async global->LDS, 16B per lane; dest = wave-uniform base + lane*16
__device__ __forceinline__ void load_lds16(const void* gsrc, void* ldst) {
    __builtin_amdgcn_global_load_lds(
        (const __attribute__((address_space(1))) void*)gsrc,
        (__attribute__((address_space(3))) void*)ldst, 16, 0, 0);
}
// bijective XCD-chunked block swizzle (m204)
__device__ __forceinline__ int xcd_swz(int bid, int nwg) {
    int q = nwg >> 3, r = nwg & 7;
    int x = bid & 7, i = bid >> 3;
    return (x < r ? x * (q + 1) : r * (q + 1) + (x - r) * q) + i;
}

// ---------------- fused weight prep: all converts/transposes in ONE launch ----------------
__global__ __launch_bounds__(256) void wprep_kernel(
        const float* __restrict__ qw, const float* __restrict__ k1,
        const float* __restrict__ k2, const float* __restrict__ pw,
        const float* __restrict__ f1, const float* __restrict__ f2,
        const float* __restrict__ cw, const float* __restrict__ lw,
        const float* __restrict__ dw,
        ushort* __restrict__ wq, ushort* __restrict__ wkv1,
        ushort* __restrict__ wkv2, ushort* __restrict__ wpr,
        ushort* __restrict__ wf1, ushort* __restrict__ wf2,
        ushort* __restrict__ wcp, float* __restrict__ lpwt,
        ushort* __restrict__ dwwth) {
    int i = blockIdx.x * 256 + threadIdx.x;
    if (i < 36864) { wq[i] = f2bf(qw[i]); return; } i -= 36864;
    if (i < 36864) { wkv1[i] = f2bf(k1[i]); return; } i -= 36864;
    if (i < 36864) { wkv2[i] = f2bf(k2[i]); return; } i -= 36864;
    if (i < 65536) { wpr[i] = f2bf(pw[i]); return; } i -= 65536;
    if (i < 262144) { wf1[i] = f2bf(f1[i]); return; } i -= 262144;
    if (i < 262144) { wf2[i] = f2h(f2[i]); return; } i -= 262144;
    if (i < 36864) {
        int co = i / 576, k = i - co * 576;
        int tap = k >> 6, ci = k & 63;
        wcp[i] = f2bf(cw[co * 576 + ci * 9 + tap]);
        return;
    } i -= 36864;
    if (i < 2304) { int c = i / 9, t = i - c * 9; lpwt[t * CC + c] = lw[i]; return; } i -= 2304;
    if (i < 9216) { int c = i / 9, t = i - c * 9; dwwth[t * HID + c] = f2h(dw[i]); }
}

// ---------------- LPU x-walk: dw3x3 + bias + residual + fused LN1; 4 px/wave ----------------
__global__ __launch_bounds__(256) void lpu_kernel(const float* __restrict__ x,
        const float* __restrict__ wt, const float* __restrict__ bias,
        const float* __restrict__ n1g, const float* __restrict__ n1b,
        ushort* __restrict__ xbuf, ushort* __restrict__ ybuf) {
    int tid = threadIdx.x;
    int lane = tid & 63, wv = tid >> 6;
    int c = lane * 4;
    int grp = xcd_swz(blockIdx.x, NN / 16) * 4 + wv;
    int n0 = grp * 4;
    int h = n0 / WW, x0 = n0 - h * WW;
    int b = blockIdx.y;
    const float* xb = x + (size_t)b * NN * CC + c;
    float4 wreg[9];
#pragma unroll
    for (int t = 0; t < 9; ++t) wreg[t] = *(const float4*)(wt + t * CC + c);
    float4 bz = *(const float4*)(bias + c);
    float4 acc[4] = {bz, bz, bz, bz};
#pragma unroll
    for (int cx = 0; cx < 6; ++cx) {
        int wx = x0 + cx - 1;
        if ((unsigned)wx >= (unsigned)WW) continue;
#pragma unroll
        for (int ky = 0; ky < 3; ++ky) {
            int hy = h + ky - 1;
            if ((unsigned)hy >= (unsigned)HH) continue;
            float4 xv = *(const float4*)(xb + (size_t)(hy * WW + wx) * CC);
#pragma unroll
            for (int xo = 0; xo < 4; ++xo) {
                int kx = cx - xo;
                if (kx < 0 || kx > 2) continue;
                float4 wv4 = wreg[ky * 3 + kx];
                acc[xo].x = fmaf(xv.x, wv4.x, acc[xo].x);
                acc[xo].y = fmaf(xv.y, wv4.y, acc[xo].y);
                acc[xo].z = fmaf(xv.z, wv4.z, acc[xo].z);
                acc[xo].w = fmaf(xv.w, wv4.w, acc[xo].w);
            }
        }
    }
    float4 gv = *(const float4*)(n1g + c);
    float4 bv = *(const float4*)(n1b + c);
#pragma unroll
    for (int xo = 0; xo < 4; ++xo) {
        size_t o = ((size_t)b * NN + n0 + xo) * CC + c;
        float4 rv = *(const float4*)(x + o);
        float4 a = acc[xo];
        a.x += rv.x; a.y += rv.y; a.z += rv.z; a.w += rv.w;
        s4v xv4;
        xv4.x = (short)f2bf(a.x);
        xv4.y = (short)f2bf(a.y);
        xv4.z = (short)f2bf(a.z);
        xv4.w = (short)f2bf(a.w);
        *(s4v*)(xbuf + o) = xv4;
        float s = a.x + a.y + a.z + a.w;
        float sq = a.x * a.x + a.y * a.y + a.z * a.z + a.w * a.w;
#pragma unroll
        for (int off = 32; off >= 1; off >>= 1) {
            s += __shfl_xor(s, off, 64);
            sq += __shfl_xor(sq, off, 64);
        }
        float mean = s * (1.0f / 256.0f);
        float var = sq * (1.0f / 256.0f) - mean * mean;
        float rstd = rsqrtf(var + 1e-5f);
        s4v ov;
        ov.x = (short)f2bf((a.x - mean) * rstd * gv.x + bv.x);
        ov.y = (short)f2bf((a.y - mean) * rstd * gv.y + bv.y);
        ov.z = (short)f2bf((a.z - mean) * rstd * gv.z + bv.z);
        ov.w = (short)f2bf((a.w - mean) * rstd * gv.w + bv.w);
        *(s4v*)(ybuf + o) = ov;
    }
}

// ---------------- cp branch body: implicit-GEMM conv + fused LN(64)+GELU (LDS passed in) ----------------
__device__ __forceinline__ void cpgemm_body(
        const ushort* __restrict__ y, const ushort* __restrict__ wt,
        const float* __restrict__ cb, const float* __restrict__ cng,
        const float* __restrict__ cnb, ushort* __restrict__ cat,
        ushort* As /*>=128*32*/, ushort* Ws /*>=64*32*/, int tile) {
    int tid = threadIdx.x;
    int wid = tid >> 6, lane = tid & 63;
    int rt = xcd_swz(tile, BNR / 128) * 128;
    int r0 = tid >> 2, c0 = tid & 3;
    int r1 = r0 + 64;
    int tok0 = rt + r0, tok1 = rt + r1;
    int b0 = tok0 / NN, n0 = tok0 - b0 * NN, h0 = n0 / WW, w0 = n0 - h0 * WW;
    int b1 = tok1 / NN, n1 = tok1 - b1 * NN, h1 = n1 / WW, w1 = n1 - h1 * WW;
    const ushort* Wp = wt + (size_t)r0 * 576 + c0 * 8;
    int aw0 = (c0 ^ (r0 & 3)) << 3;
    f4v acc[2][4];
#pragma unroll
    for (int m = 0; m < 2; ++m)
#pragma unroll
        for (int n = 0; n < 4; ++n) acc[m][n] = (f4v)0.f;
    int lr = lane & 15, g4 = lane >> 4;
    int swz = (g4 ^ (lr & 3)) << 3;
    for (int kt = 0; kt < 576; kt += 32) {
        int tap = kt >> 6, ci0 = kt & 63;
        int t3 = tap / 3, dy = t3 - 1, dx = (tap - t3 * 3) - 1;
        s8v a0 = (s8v)0, a1 = (s8v)0;
        int hy0 = h0 + dy, wx0 = w0 + dx;
        if ((unsigned)hy0 < (unsigned)HH && (unsigned)wx0 < (unsigned)WW)
            a0 = *(const s8v*)(y + ((size_t)b0 * NN + hy0 * WW + wx0) * CC + ci0 + c0 * 8);
        int hy1 = h1 + dy, wx1 = w1 + dx;
        if ((unsigned)hy1 < (unsigned)HH && (unsigned)wx1 < (unsigned)WW)
            a1 = *(const s8v*)(y + ((size_t)b1 * NN + hy1 * WW + wx1) * CC + ci0 + c0 * 8);
        s8v wv = *(const s8v*)(Wp + kt);
        __syncthreads();
        *(s8v*)&As[r0 * 32 + aw0] = a0;
        *(s8v*)&As[r1 * 32 + aw0] = a1;
        *(s8v*)&Ws[r0 * 32 + aw0] = wv;
        __syncthreads();
        s8v af[2], bf[4];
#pragma unroll
        for (int m = 0; m < 2; ++m)
            af[m] = *(const s8v*)&As[(wid * 32 + m * 16 + lr) * 32 + swz];
#pragma unroll
        for (int n = 0; n < 4; ++n)
            bf[n] = *(const s8v*)&Ws[(n * 16 + lr) * 32 + swz];
#pragma unroll
        for (int m = 0; m < 2; ++m)
#pragma unroll
            for (int n = 0; n < 4; ++n)
                acc[m][n] = __builtin_amdgcn_mfma_f32_16x16x32_bf16(af[m], bf[n], acc[m][n], 0, 0, 0);
    }
    float gv[4], bv[4], cbv[4];
#pragma unroll
    for (int n = 0; n < 4; ++n) {
        int gc = n * 16 + lr;
        cbv[n] = cb[gc];
        gv[n] = cng[gc];
        bv[n] = cnb[gc];
    }
#pragma unroll
    for (int m = 0; m < 2; ++m)
#pragma unroll
        for (int r = 0; r < 4; ++r) {
            float s = 0.f, sq = 0.f;
#pragma unroll
            for (int n = 0; n < 4; ++n) {
                float v = acc[m][n][r] + cbv[n];
                acc[m][n][r] = v;
                s += v; sq += v * v;
            }
#pragma unroll
            for (int off = 1; off < 16; off <<= 1) {
                s += __shfl_xor(s, off, 64);
                sq += __shfl_xor(sq, off, 64);
            }
            float mean = s * (1.0f / 64.0f);
            float var = sq * (1.0f / 64.0f) - mean * mean;
            float rstd = rsqrtf(var + 1e-5f);
            int row = rt + wid * 32 + m * 16 + g4 * 4 + r;
            ushort* op = cat + (size_t)row * CC + 192;
#pragma unroll
            for (int n = 0; n < 4; ++n) {
                float v = (acc[m][n][r] - mean) * rstd * gv[n] + bv[n];
                op[n * 16 + lr] = f2bf(gelu_f(v));
            }
        }
}

// ---------------- SR conv body (depthwise KSxKS stride KS) + LN(192) + GELU, bf16 io ----------------
template <int KS, int OW>
__device__ __forceinline__ void sr_body(const ushort* __restrict__ yap,
        const float* __restrict__ w, const float* __restrict__ bias,
        const float* __restrict__ g, const float* __restrict__ bt,
        ushort* __restrict__ out, int m, int b) {
    int ch = threadIdx.x;
    int oh = m / OW, ow = m - oh * OW;
    const ushort* yb = yap + (size_t)b * NN * CC;
    float acc = bias[ch];
#pragma unroll
    for (int ky = 0; ky < KS; ++ky)
#pragma unroll
        for (int kx = 0; kx < KS; ++kx)
            acc = fmaf(bf2f(yb[(size_t)((oh * KS + ky) * WW + ow * KS + kx) * CC + ch]),
                       w[ch * KS * KS + ky * KS + kx], acc);
    __shared__ float red[2][3];
    float s = acc, sq = acc * acc;
#pragma unroll
    for (int off = 32; off >= 1; off >>= 1) {
        s += __shfl_xor(s, off, 64);
        sq += __shfl_xor(sq, off, 64);
    }
    int wv = threadIdx.x >> 6, lane = threadIdx.x & 63;
    if (lane == 0) { red[0][wv] = s; red[1][wv] = sq; }
    __syncthreads();
    s = red[0][0] + red[0][1] + red[0][2];
    sq = red[1][0] + red[1][1] + red[1][2];
    float mean = s * (1.0f / 192.0f);
    float var = sq * (1.0f / 192.0f) - mean * mean;
    float rstd = rsqrtf(var + 1e-5f);
    float v = (acc - mean) * rstd * g[ch] + bt[ch];
    out[((size_t)b * (OW * OW) + m) * AD + ch] = f2bf(gelu_f(v));
}

// merged SR convs: blockIdx.x in [0,M2) -> sr2 (4x4); [M2,M2+M1) -> sr1 (8x8)
__global__ __launch_bounds__(192) void sr_both(const ushort* __restrict__ yap,
        const float* __restrict__ w1, const float* __restrict__ b1,
        const float* __restrict__ g1, const float* __restrict__ t1,
        ushort* __restrict__ o1,
        const float* __restrict__ w2, const float* __restrict__ b2,
        const float* __restrict__ g2, const float* __restrict__ t2,
        ushort* __restrict__ o2) {
    int b = blockIdx.y;
    if (blockIdx.x < M2) sr_body<4, 14>(yap, w2, b2, g2, t2, o2, blockIdx.x, b);
    else                 sr_body<8, 7>(yap, w1, b1, g1, t1, o1, blockIdx.x - M2, b);
}

// ---------------- MFMA GEMM body: 256x128 tile, 512 thr / 8 waves, 2-phase ----------------
// MODE bits: 1=bias(fp32), 2=residual(bf16, stride ldr), 4=output bf16, 8=output f16 (else fp32)
template <int MODE, int F16>
__device__ __forceinline__ void gemm_body(
        const ushort* __restrict__ A, int lda,
        const ushort* __restrict__ W, int K, int O,
        const float* __restrict__ bias,
        const ushort* __restrict__ res, int ldr,
        void* __restrict__ Cout, int ldc, int R,
        int gx, int nwg, int bid) {
    __shared__ __align__(16) ushort As[2 * 256 * 32];   // 32KB
    __shared__ __align__(16) ushort Ws[2 * 128 * 32];   // 16KB
    int tid = threadIdx.x;
    int w8 = tid >> 6, lane = tid & 63;
    int wr = w8 >> 1, wc = w8 & 1;
    int swzb = xcd_swz(bid, nwg);
    int rt = (swzb / gx) * 256, ot = (swzb % gx) * 128;
    int r0 = tid >> 2, cslot = tid & 3;
    int csrc = (cslot ^ (r0 & 3)) * 8;
    const ushort* Ap0 = A + (size_t)min(rt + r0, R - 1) * lda + csrc;
    const ushort* Ap1 = A + (size_t)min(rt + r0 + 128, R - 1) * lda + csrc;
    const ushort* Wp0 = W + (size_t)min(ot + r0, O - 1) * K + csrc;
    char* lA0 = (char*)As + w8 * 1024;
    char* lA1 = (char*)As + 8192 + w8 * 1024;
    char* lW0 = (char*)Ws + w8 * 1024;
    f4v acc[4][4];
#pragma unroll
    for (int m = 0; m < 4; ++m)
#pragma unroll
        for (int n = 0; n < 4; ++n) acc[m][n] = (f4v)0.f;
    int lr = lane & 15;
    int swz = ((lane >> 4) ^ (lr & 3)) << 3;
    load_lds16(Ap0, lA0);
    load_lds16(Ap1, lA1);
    load_lds16(Wp0, lW0);
    __syncthreads();
    int cur = 0;
    for (int kt = 0; kt < K; kt += 32) {
        if (kt + 32 < K) {
            int pa = (cur ^ 1) * 16384, pw = (cur ^ 1) * 8192;
            load_lds16(Ap0 + kt + 32, lA0 + pa);
            load_lds16(Ap1 + kt + 32, lA1 + pa);
            load_lds16(Wp0 + kt + 32, lW0 + pw);
        }
        const ushort* Ab = As + cur * 8192;
        const ushort* Wb = Ws + cur * 4096;
        s8v af[4], bf[4];
#pragma unroll
        for (int m = 0; m < 4; ++m)
            af[m] = *(const s8v*)&Ab[(wr * 64 + m * 16 + lr) * 32 + swz];
#pragma unroll
        for (int n = 0; n < 4; ++n)
            bf[n] = *(const s8v*)&Wb[(wc * 64 + n * 16 + lr) * 32 + swz];
#pragma unroll
        for (int m = 0; m < 4; ++m)
#pragma unroll
            for (int n = 0; n < 4; ++n) {
                if (F16) {
                    h8v ah = *(const h8v*)&af[m];
                    h8v bh = *(const h8v*)&bf[n];
                    acc[m][n] = __builtin_amdgcn_mfma_f32_16x16x32_f16(ah, bh, acc[m][n], 0, 0, 0);
                } else {
                    acc[m][n] = __builtin_amdgcn_mfma_f32_16x16x32_bf16(af[m], bf[n], acc[m][n], 0, 0, 0);
                }
            }
        __syncthreads();
        cur ^= 1;
    }
#pragma unroll
    for (int m = 0; m < 4; ++m)
#pragma unroll
        for (int n = 0; n < 4; ++n) {
            int gr = rt + wr * 64 + m * 16 + (lane >> 4) * 4;
            int gc = ot + wc * 64 + n * 16 + (lane & 15);
            if (gc >= O) continue;
#pragma unroll
            for (int r = 0; r < 4; ++r) {
                int row = gr + r;
                if (row >= R) continue;
                float v = acc[m][n][r];
                if (MODE & 1) v += bias[gc];
                if (MODE & 2) v += bf2f(res[(size_t)row * ldr + gc]);
                if (MODE & 4)      ((ushort*)Cout)[(size_t)row * ldc + gc] = f2bf(v);
                else if (MODE & 8) ((ushort*)Cout)[(size_t)row * ldc + gc] = f2h(v);
                else               ((float*)Cout)[(size_t)row * ldc + gc] = v;
            }
        }
}

// merged q + kv GEMMs: blockIdx.z selects problem (0=q, 1=kv1 y<4, 2=kv2 y<13)
__global__ __launch_bounds__(512) void kvq_all(
        const ushort* __restrict__ yap, const ushort* __restrict__ wq,
        ushort* __restrict__ qbuf,
        const ushort* __restrict__ x1g, const ushort* __restrict__ wkv1,
        ushort* __restrict__ kv1b,
        const ushort* __restrict__ x2g, const ushort* __restrict__ wkv2,
        ushort* __restrict__ kv2b) {
    int bid = blockIdx.y * 2 + blockIdx.x;
    if (blockIdx.z == 0) {
        gemm_body<4, 0>(yap, CC, wq, AD, AD, nullptr, nullptr, 0,
                        qbuf, AD, BNR, 2, 392, bid);
    } else if (blockIdx.z == 1) {
        if (blockIdx.y >= 4) return;
        gemm_body<4, 0>(x1g, AD, wkv1, AD, AD, nullptr, nullptr, 0,
                        kv1b, AD, BB * M1, 2, 8, bid);
    } else {
        if (blockIdx.y >= 13) return;
        gemm_body<4, 0>(x2g, AD, wkv2, AD, AD, nullptr, nullptr, 0,
                        kv2b, AD, BB * M2, 2, 26, bid);
    }
}

// ---------------- 16-wave 8-phase GEMM: 256x256 tile, BK=64, counted vmcnt, depth-3 ----------------
// (R25 best-measured: 1024 thr / 16 waves (4x4), wave 64x64 out, 128KB LDS, vmcnt(4) steady)
template <int MODE, int F16 = 0>
__global__ __launch_bounds__(1024) void gemm_8ph(
        const ushort* __restrict__ A, int lda,
        const ushort* __restrict__ W, int K, int O,
        const float* __restrict__ bias,
        const ushort* __restrict__ res, int ldr,
        void* __restrict__ Cout, int ldc, int R) {
    __shared__ __align__(16) ushort Al[2 * 256 * 64];   // 64KB
    __shared__ __align__(16) ushort Wl[2 * 256 * 64];   // 64KB
    int tid = threadIdx.x;
    int w16 = tid >> 6, lane = tid & 63;
    int wr = w16 >> 2, wc = w16 & 3;          // 4 x 4 wave grid
    int nwg = gridDim.x * gridDim.y;
    int swzb = xcd_swz(blockIdx.y * gridDim.x + blockIdx.x, nwg);
    int rt = (swzb / gridDim.x) * 256, ot = (swzb % gridDim.x) * 256;
    int lr = lane & 15, g4 = lane >> 4;
    int swz = (g4 ^ (lr & 3)) << 3;
    int ar0 = tid >> 2, sp0 = tid & 3;        // 1024 units cover all 256 rows x 4 slots
    int cs0 = ((sp0 ^ (ar0 & 3)) << 3);       // inverse-swizzled source K-slot
    const ushort* Ap0 = A + (size_t)(rt + ar0) * lda + cs0;
    const ushort* Wp0 = W + (size_t)(ot + ar0) * K + cs0;
    int d0 = w16 * 1024;                       // LDS dest byte offset (lane*16 implicit)
    f4v acc[4][4];
#pragma unroll
    for (int m = 0; m < 4; ++m)
#pragma unroll
        for (int n = 0; n < 4; ++n)
            acc[m][n] = (f4v)((MODE & 1) ? bias[ot + wc * 64 + n * 16 + lr] : 0.0f);
    auto STAGE = [&](int s) {
        int t = s >> 1, hf = s & 1;
        int boff = (t & 1) * 32768 + hf * 16384;   // byte offset in each LDS array
        int kc = t * 64 + hf * 32;
        load_lds16(Ap0 + kc, (char*)Al + boff + d0);
        load_lds16(Wp0 + kc, (char*)Wl + boff + d0);
    };
    int nS = K >> 5;                           // half-stages (32-K each)
    STAGE(0); STAGE(1); STAGE(2);
    for (int s = 0; s < nS; ++s) {
        if (s < nS - 2)       asm volatile("s_waitcnt vmcnt(4)" ::: "memory");
        else if (s == nS - 2) asm volatile("s_waitcnt vmcnt(2)" ::: "memory");
        else                  asm volatile("s_waitcnt vmcnt(0)" ::: "memory");
        __builtin_amdgcn_s_barrier();
        __builtin_amdgcn_sched_barrier(0);
        if (s + 3 < nS) STAGE(s + 3);
        int uoff = ((s >> 1) & 1) * 16384 + (s & 1) * 8192;   // ushort index offset
        const ushort* Ab = Al + uoff;
        const ushort* Wb = Wl + uoff;
        s8v af[4], bf[4];
#pragma unroll
        for (int m = 0; m < 4; ++m)
            af[m] = *(const s8v*)&Ab[(wr * 64 + m * 16 + lr) * 32 + swz];
#pragma unroll
        for (int n = 0; n < 4; ++n)
            bf[n] = *(const s8v*)&Wb[(wc * 64 + n * 16 + lr) * 32 + swz];
        __builtin_amdgcn_s_setprio(1);
#pragma unroll
        for (int m = 0; m < 4; ++m)
#pragma unroll
            for (int n = 0; n < 4; ++n) {
                if (F16) {
                    h8v ah = *(const h8v*)&af[m];
                    h8v bh = *(const h8v*)&bf[n];
                    acc[m][n] = __builtin_amdgcn_mfma_f32_16x16x32_f16(ah, bh, acc[m][n], 0, 0, 0);
                } else {
                    acc[m][n] = __builtin_amdgcn_mfma_f32_16x16x32_bf16(af[m], bf[n], acc[m][n], 0, 0, 0);
                }
            }
        __builtin_amdgcn_s_setprio(0);
    }
#pragma unroll
    for (int m = 0; m < 4; ++m) {
        int gr = rt + wr * 64 + m * 16 + g4 * 4;
#pragma unroll
        for (int n = 0; n < 4; ++n) {
            int gc = ot + wc * 64 + n * 16 + lr;
#pragma unroll
            for (int r = 0; r < 4; ++r) {
                int row = gr + r;
                float v = acc[m][n][r];
                if (MODE & 2) v += bf2f(res[(size_t)row * ldr + gc]);
                if (MODE & 4)      ((ushort*)Cout)[(size_t)row * ldc + gc] = f2bf(v);
                else if (MODE & 8) ((ushort*)Cout)[(size_t)row * ldc + gc] = f2h(v);
                else               ((float*)Cout)[(size_t)row * ldc + gc] = v;
            }
        }
    }
}

// ---------------- proj (O=256) + bias + residual + fused LN2 ----------------
__global__ __launch_bounds__(512) void projln_kernel(
        const ushort* __restrict__ A, const ushort* __restrict__ W,
        const float* __restrict__ bias,
        const float* __restrict__ n2g, const float* __restrict__ n2b,
        ushort* __restrict__ xbuf, ushort* __restrict__ ybuf) {
    __shared__ __align__(16) ushort As[128 * 32];   // 8KB
    __shared__ __align__(16) ushort Ws[256 * 32];   // 16KB
    int tid = threadIdx.x;
    int w8 = tid >> 6, lane = tid & 63;
    int rt = xcd_swz(blockIdx.x, BNR / 128) * 128;
    int r0 = tid >> 2, cslot = tid & 3;
    int csrc = (cslot ^ (r0 & 3)) * 8;
    const ushort* Ap0 = A + (size_t)(rt + r0) * CC + csrc;
    const ushort* Wp0 = W + (size_t)r0 * CC + csrc;
    const ushort* Wp1 = W + (size_t)(r0 + 128) * CC + csrc;
    char* lA0 = (char*)As + w8 * 1024;
    char* lW0 = (char*)Ws + w8 * 1024;
    char* lW1 = (char*)Ws + 8192 + w8 * 1024;
    int lr = lane & 15, g4 = lane >> 4;
    int swz = (g4 ^ (lr & 3)) << 3;
    f4v acc[16];
#pragma unroll
    for (int n = 0; n < 16; ++n) acc[n] = (f4v)(bias[n * 16 + lr]);
    for (int kt = 0; kt < CC; kt += 32) {
        __syncthreads();
        load_lds16(Ap0 + kt, lA0);
        load_lds16(Wp0 + kt, lW0);
        load_lds16(Wp1 + kt, lW1);
        __syncthreads();
        s8v af = *(const s8v*)&As[(w8 * 16 + lr) * 32 + swz];
#pragma unroll
        for (int n = 0; n < 16; ++n) {
            s8v bf = *(const s8v*)&Ws[(n * 16 + lr) * 32 + swz];
            acc[n] = __builtin_amdgcn_mfma_f32_16x16x32_bf16(af, bf, acc[n], 0, 0, 0);
        }
    }
#pragma unroll
    for (int r = 0; r < 4; ++r) {
        int row = rt + w8 * 16 + g4 * 4 + r;
        ushort* xr = xbuf + (size_t)row * CC;
        ushort* yr = ybuf + (size_t)row * CC;
        float s = 0.f, sq = 0.f;
#pragma unroll
        for (int n = 0; n < 16; ++n) {
            float v = acc[n][r] + bf2f(xr[n * 16 + lr]);
            acc[n][r] = v;
            s += v; sq += v * v;
        }
#pragma unroll
        for (int off = 1; off < 16; off <<= 1) {
            s += __shfl_xor(s, off, 64);
            sq += __shfl_xor(sq, off, 64);
        }
        float mean = s * (1.0f / 256.0f);
        float var = sq * (1.0f / 256.0f) - mean * mean;
        float rstd = rsqrtf(var + 1e-5f);
#pragma unroll
        for (int n = 0; n < 16; ++n) {
            int col = n * 16 + lr;
            float v = acc[n][r];
            xr[col] = f2bf(v);
            yr[col] = f2bf((v - mean) * rstd * n2g[col] + n2b[col]);
        }
    }
}

// ---------------- MFMA attention body (shared by both K/V groups) ----------------
template <int M, int MP>
__device__ __forceinline__ void attn_body(const ushort* __restrict__ q,
        const ushort* __restrict__ kvb, ushort* __restrict__ cat,
        ushort* Kl, ushort* VT, int g, int h, int b) {
    constexpr int NT = MP / 16;
    constexpr int NCH = MP / 32;
    int tid = threadIdx.x;
    for (int i = tid; i < MP * 4; i += 256) ((s8v*)Kl)[i] = (s8v)0;
    for (int i = tid; i < MP * 4; i += 256) ((s8v*)VT)[i] = (s8v)0;
    __syncthreads();
    for (int u = tid; u < M * 3; u += 256) {
        int m = u / 3, d0 = u - m * 3;
        s8v kv8 = *(const s8v*)(kvb + ((size_t)b * M + m) * AD + g * HD + d0 * 8);
        *(s8v*)&Kl[m * 32 + ((d0 ^ (m & 3)) << 3)] = kv8;
    }
    for (int u = tid; u < M * 3; u += 256) {
        int m = u / 3, d0 = u - m * 3;
        s8v vv = *(const s8v*)(kvb + ((size_t)b * M + m) * AD + 96 + g * HD + d0 * 8);
        int c = m >> 5, mm = m & 31;
        int gg = (mm >> 2) & 3;
        int t = (mm & 3) + ((mm & 16) >> 2);
#pragma unroll
        for (int j = 0; j < 8; ++j) {
            int d = d0 * 8 + j;
            VT[d * MP + ((c * 4 + (gg ^ (d & 3))) << 3) + t] = (ushort)vv[j];
        }
    }
    __syncthreads();
    int w = tid >> 6, lane = tid & 63;
    int ln = lane & 15, g4 = lane >> 4;
    int swz = (g4 ^ (ln & 3)) << 3;
    const float scale = 0.20412414523193154f;  // 24^-0.5
    for (int nt = 0; nt < 4; ++nt) {
        int nbase = blockIdx.x * 256 + nt * 64;
        if (nbase >= NN) break;
        int n0 = nbase + w * 16 + ln;
        s8v qf = (s8v)0;
        if (g4 < 3) qf = *(const s8v*)(q + ((size_t)b * NN + n0) * AD + h * HD + g4 * 8);
        f4v sa[NT];
#pragma unroll
        for (int t = 0; t < NT; ++t) sa[t] = (f4v)0.f;
#pragma unroll
        for (int t = 0; t < NT; ++t) {
            s8v kf = *(const s8v*)&Kl[(t * 16 + ln) * 32 + swz];
            sa[t] = __builtin_amdgcn_mfma_f32_16x16x32_bf16(kf, qf, sa[t], 0, 0, 0);
        }
        float mx = -3.0e38f;
#pragma unroll
        for (int t = 0; t < NT; ++t)
#pragma unroll
            for (int r = 0; r < 4; ++r) {
                int m = t * 16 + g4 * 4 + r;
                float v = (m < M) ? sa[t][r] * scale : -3.0e38f;
                sa[t][r] = v;
                mx = fmaxf(mx, v);
            }
        mx = fmaxf(mx, __shfl_xor(mx, 16, 64));
        mx = fmaxf(mx, __shfl_xor(mx, 32, 64));
        float sum = 0.f;
#pragma unroll
        for (int t = 0; t < NT; ++t)
#pragma unroll
            for (int r = 0; r < 4; ++r) {
                float p = __expf(sa[t][r] - mx);
                sa[t][r] = p;
                sum += p;
            }
        sum += __shfl_xor(sum, 16, 64);
        sum += __shfl_xor(sum, 32, 64);
        float inv = 1.0f / sum;
        f4v oa[2] = {(f4v)0.f, (f4v)0.f};
#pragma unroll
        for (int c = 0; c < NCH; ++c) {
            s8v pb;
#pragma unroll
            for (int t = 0; t < 4; ++t) {
                pb[t]     = (short)f2bf(sa[c * 2][t]);
                pb[4 + t] = (short)f2bf(sa[c * 2 + 1][t]);
            }
#pragma unroll
            for (int dt = 0; dt < 2; ++dt) {
                s8v vf = *(const s8v*)&VT[(dt * 16 + ln) * MP + c * 32 + swz];
                oa[dt] = __builtin_amdgcn_mfma_f32_16x16x32_bf16(vf, pb, oa[dt], 0, 0, 0);
            }
        }
        ushort* op = cat + ((size_t)b * NN + n0) * CC + h * HD;
        s4v o0;
#pragma unroll
        for (int r = 0; r < 4; ++r) o0[r] = (short)f2bf(oa[0][r] * inv);
        *(s4v*)(op + g4 * 4) = o0;
        if (g4 < 2) {
            s4v o1;
#pragma unroll
            for (int r = 0; r < 4; ++r) o1[r] = (short)f2bf(oa[1][r] * inv);
            *(s4v*)(op + 16 + g4 * 4) = o1;
        }
    }
}

// merged attention + cp-conv: blockIdx.y in [0,8) covers both K/V groups;
// y==8 plane runs the cp implicit-GEMM conv tiles (reuses attention LDS)
__global__ __launch_bounds__(256) void attn_both(const ushort* __restrict__ q,
        const ushort* __restrict__ kv1b, const ushort* __restrict__ kv2b,
        ushort* __restrict__ cat,
        const ushort* __restrict__ ybuf, const ushort* __restrict__ wcp,
        const float* __restrict__ cb, const float* __restrict__ cng,
        const float* __restrict__ cnb) {
    __shared__ __align__(16) ushort Kl[224 * 32];
    __shared__ __align__(16) ushort VT[32 * 224];
    int hy = blockIdx.y, b = blockIdx.z;
    if (hy < HG)      attn_body<M1, 64>(q, kv1b, cat, Kl, VT, hy, hy, b);
    else if (hy < NH) attn_body<M2, 224>(q, kv2b, cat, Kl, VT, hy - HG, hy, b);
    else {
        int id = blockIdx.x + 13 * blockIdx.z;   // 208 plane blocks
        for (int t = id * 2; t < id * 2 + 2; ++t)
            if (t < BNR / 128)
                cpgemm_body(ybuf, wcp, cb, cng, cnb, cat, Kl, VT, t);
    }
}

// ---------------- depthwise 3x3 hid=1024: x-walk, f16 packed math ----------------
__global__ __launch_bounds__(256) void dwconv_kernel(const ushort* __restrict__ z1,
        const ushort* __restrict__ wt, const float* __restrict__ bias,
        ushort* __restrict__ z2) {
    int bid = xcd_swz(blockIdx.x, HH * 7);
    int h = bid / 7, bx = bid - h * 7;
    int b = blockIdx.y;
    int c = (threadIdx.x & 127) * 8;
    int x0 = bx * 8 + (threadIdx.x >> 7) * 4;
    const ushort* zrow = z1 + ((size_t)b * NN + h * WW) * HID + c;
    h2v wreg[9][4];
#pragma unroll
    for (int t = 0; t < 9; ++t) {
        s8v w8 = *(const s8v*)(wt + t * HID + c);
        const h2v* wp = (const h2v*)&w8;
#pragma unroll
        for (int p = 0; p < 4; ++p) wreg[t][p] = wp[p];
    }
    h2v acc[4][4];
    {
        float4 b0 = *(const float4*)(bias + c);
        float4 b1 = *(const float4*)(bias + c + 4);
        h2v bz[4];
        bz[0][0] = (_Float16)b0.x; bz[0][1] = (_Float16)b0.y;
        bz[1][0] = (_Float16)b0.z; bz[1][1] = (_Float16)b0.w;
        bz[2][0] = (_Float16)b1.x; bz[2][1] = (_Float16)b1.y;
        bz[3][0] = (_Float16)b1.z; bz[3][1] = (_Float16)b1.w;
#pragma unroll
        for (int xo = 0; xo < 4; ++xo)
#pragma unroll
            for (int p = 0; p < 4; ++p) acc[xo][p] = bz[p];
    }
#pragma unroll
    for (int cx = 0; cx < 6; ++cx) {
        int wx = x0 + cx - 1;
        if ((unsigned)wx >= (unsigned)WW) continue;
#pragma unroll
        for (int ky = 0; ky < 3; ++ky) {
            int hy = h + ky - 1;
            if ((unsigned)hy >= (unsigned)HH) continue;
            s8v v = *(const s8v*)(zrow + ((size_t)(ky - 1) * WW + wx) * HID);
            const h2v* v2 = (const h2v*)&v;
#pragma unroll
            for (int xo = 0; xo < 4; ++xo) {
                int kx = cx - xo;
                if (kx < 0 || kx > 2) continue;
#pragma unroll
                for (int p = 0; p < 4; ++p)
                    acc[xo][p] = v2[p] * wreg[ky * 3 + kx][p] + acc[xo][p];
            }
        }
    }
    ushort* zo = z2 + ((size_t)b * NN + h * WW + x0) * HID + c;
#pragma unroll
    for (int xo = 0; xo < 4; ++xo) {
        s8v o;
#pragma unroll
        for (int p = 0; p < 4; ++p) {
            o[p * 2]     = (short)f2h(gelu_f((float)acc[xo][p][0]));
            o[p * 2 + 1] = (short)f2h(gelu_f((float)acc[xo][p][1]));
        }
        *(s8v*)(zo + (size_t)xo * HID) = o;
    }
}

extern "C" void kernel_launch(void* const* d_in, const int* in_sizes, int n_in,
                              void* d_out, int out_size, void* d_ws, size_t ws_size,
                              hipStream_t stream) {
    const float* x      = (const float*)d_in[0];
    const float* lpu_w  = (const float*)d_in[3];
    const float* lpu_b  = (const float*)d_in[4];
    const float* n1_g   = (const float*)d_in[5];
    const float* n1_b   = (const float*)d_in[6];
    const float* c2_w   = (const float*)d_in[7];
    const float* c2_b   = (const float*)d_in[8];
    const float* cn_g   = (const float*)d_in[9];
    const float* cn_b   = (const float*)d_in[10];
    const float* q_w    = (const float*)d_in[11];
    const float* sr1_w  = (const float*)d_in[12];
    const float* sr1_b  = (const float*)d_in[13];
    const float* an1_g  = (const float*)d_in[14];
    const float* an1_b  = (const float*)d_in[15];
    const float* sr2_w  = (const float*)d_in[16];
    const float* sr2_b  = (const float*)d_in[17];
    const float* an2_g  = (const float*)d_in[18];
    const float* an2_b  = (const float*)d_in[19];
    const float* kv1_w  = (const float*)d_in[20];
    const float* kv2_w  = (const float*)d_in[21];
    const float* proj_w = (const float*)d_in[22];
    const float* proj_b = (const float*)d_in[23];
    const float* n2_g   = (const float*)d_in[24];
    const float* n2_b   = (const float*)d_in[25];
    const float* fc1_w  = (const float*)d_in[26];
    const float* fc1_b  = (const float*)d_in[27];
    const float* dw_w   = (const float*)d_in[28];
    const float* dw_b   = (const float*)d_in[29];
    const float* fc2_w  = (const float*)d_in[30];
    const float* fc2_b  = (const float*)d_in[31];
    float* out = (float*)d_out;

    char* ws = (char*)d_ws;
    size_t off = 0;
    auto allocB = [&](size_t bytes) {
        char* p = ws + off;
        off += ((bytes + 255) & ~(size_t)255);
        return p;
    };
    ushort* xbuf = (ushort*)allocB((size_t)BNR * CC * 2);  // bf16 residual spine
    ushort* ybuf = (ushort*)allocB((size_t)BNR * CC * 2);  // LN out (bf16)
    ushort* wq   = (ushort*)allocB((size_t)AD * AD * 2);
    ushort* wkv1 = (ushort*)allocB((size_t)AD * AD * 2);
    ushort* wkv2 = (ushort*)allocB((size_t)AD * AD * 2);
    ushort* wpr  = (ushort*)allocB((size_t)CC * CC * 2);
    ushort* wf1  = (ushort*)allocB((size_t)HID * CC * 2);
    ushort* wf2  = (ushort*)allocB((size_t)CC * HID * 2);  // f16
    ushort* wcp  = (ushort*)allocB((size_t)64 * 576 * 2);
    float*  lpwt = (float*)allocB((size_t)9 * CC * 4);
    ushort* dwwt = (ushort*)allocB((size_t)9 * HID * 2);   // f16
    size_t zmark = off;                                    // overlay region start
    ushort* cat  = (ushort*)allocB((size_t)BNR * CC * 2);  // [o1|o2|cp] bf16
    ushort* qbuf = (ushort*)allocB((size_t)BNR * AD * 2);
    ushort* x1g  = (ushort*)allocB((size_t)BB * M1 * AD * 2);
    ushort* x2g  = (ushort*)allocB((size_t)BB * M2 * AD * 2);
    ushort* kv1b = (ushort*)allocB((size_t)BB * M1 * AD * 2);  // bf16 kv
    ushort* kv2b = (ushort*)allocB((size_t)BB * M2 * AD * 2);

    int CB2 = 1;
    for (int cb = 16; cb >= 1; cb >>= 1) {
        if (zmark + 2 * (size_t)cb * NN * HID * 2 <= ws_size) { CB2 = cb; break; }
    }

    dim3 b256(256), b512(512), b1024(1024);
    // 0. fused weight prep (one launch)
    wprep_kernel<<<dim3(2925), b256, 0, stream>>>(
        q_w, kv1_w, kv2_w, proj_w, fc1_w, fc2_w, c2_w, lpu_w, dw_w,
        wq, wkv1, wkv2, wpr, wf1, wf2, wcp, lpwt, dwwt);
    // 1. LPU x-walk + residual + fused LN1 (xbuf bf16 + ybuf bf16)
    lpu_kernel<<<dim3(NN / 16, BB), b256, 0, stream>>>(x, lpwt, lpu_b, n1_g, n1_b, xbuf, ybuf);
    // 2. SR convs (both) + LN + GELU, one dispatch
    sr_both<<<dim3(M1 + M2, BB), dim3(192), 0, stream>>>(ybuf + CD,
        sr1_w, sr1_b, an1_g, an1_b, x1g, sr2_w, sr2_b, an2_g, an2_b, x2g);
    // 3. q + kv GEMMs in one dispatch (bf16 out)
    kvq_all<<<dim3(2, 196, 3), b512, 0, stream>>>(
        ybuf + CD, wq, qbuf, x1g, wkv1, kv1b, x2g, wkv2, kv2b);
    // 4. attention (both groups) + cp-conv plane -> cat
    attn_both<<<dim3((NN + 255) / 256, NH + 1, BB), b256, 0, stream>>>(
        qbuf, kv1b, kv2b, cat, ybuf, wcp, c2_b, cn_g, cn_b);
    // 5. proj + bias + residual + fused LN2 (bf16 spine; writes xbuf AND ybuf)
    projln_kernel<<<dim3(BNR / 128), b512, 0, stream>>>(
        cat, wpr, proj_b, n2_g, n2_b, xbuf, ybuf);
    // 6. MLP (CB2=16 -> single pass); fc1/fc2 use the 16-wave 8-phase GEMM (R25 config)
    ushort* z1 = (ushort*)(ws + zmark);
    ushort* z2 = z1 + (size_t)CB2 * NN * HID;
    for (int c0 = 0; c0 < BB; c0 += CB2) {
        size_t tokoff = (size_t)c0 * NN;
        int Rr = CB2 * NN;
        gemm_8ph<9><<<dim3(HID / 256, Rr / 256), b1024, 0, stream>>>(
            ybuf + tokoff * CC, CC, wf1, CC, HID, fc1_b, nullptr, 0, z1, HID, Rr);
        dwconv_kernel<<<dim3(HH * 7, CB2), b256, 0, stream>>>(z1, dwwt, dw_b, z2);
        gemm_8ph<3, 1><<<dim3(CC / 256, Rr / 256), b1024, 0, stream>>>(
            z2, HID, wf2, HID, CC, fc2_b, xbuf + tokoff * CC, CC, out + tokoff * CC, CC, Rr);
    }
}